// Round 11
// baseline (486.729 us; speedup 1.0000x reference)
//
#include <hip/hip_runtime.h>
#include <hip/hip_bf16.h>

#define N_NODES 20000
#define N_EDGES 320000
#define DIM 128
#define HEADS 3
#define LAYERS 3
#define NGRAPH 64
#define NEG_SLOPE 0.2f

typedef const __hip_bfloat16* bfp;
typedef __hip_bfloat16 bf16;
typedef short v8s __attribute__((ext_vector_type(8)));
typedef float v4f __attribute__((ext_vector_type(4)));
typedef unsigned v3u __attribute__((ext_vector_type(3)));

#define GLD_LDS(gp, lp) \
    __builtin_amdgcn_global_load_lds( \
        (const __attribute__((address_space(1))) void*)(gp), \
        (__attribute__((address_space(3))) void*)(lp), 16, 0, 0)

__device__ __forceinline__ float b2f(unsigned short u) {
    return __uint_as_float(((unsigned)u) << 16);
}
__device__ __forceinline__ float lo2f(unsigned u) { return __uint_as_float(u << 16); }
__device__ __forceinline__ float hi2f(unsigned u) { return __uint_as_float(u & 0xffff0000u); }
__device__ __forceinline__ float leaky(float z) {
    return z >= 0.f ? z : NEG_SLOPE * z;
}
__device__ __forceinline__ unsigned packbf(float a, float b) {
    bf16 x = __float2bfloat16(a), y = __float2bfloat16(b);
    return (unsigned)*(unsigned short*)&x | ((unsigned)*(unsigned short*)&y << 16);
}
__device__ __forceinline__ unsigned short f2bfbits(float v) {
    bf16 x = __float2bfloat16(v);
    return *(unsigned short*)&x;
}

// Stage a 128x32 bf16 tile (rows t0..t0+127, cols k0..k0+31 of row-major [*,K])
// into LDS in GRANULE layout: granule g = kchunk*128 + row (kchunk = k/8),
// LDS shorts addr = g*8. Source addr is per-lane (free); dst is lane-contiguous
// as global_load_lds requires. Fragment reads then have 4-dword row stride ->
// 2-way bank aliasing only (free on CDNA4).
__device__ __forceinline__ void stage_tile(const short* base, int t0, int K,
                                           int k0, short* lds, int tid) {
#pragma unroll
    for (int j = 0; j < 2; ++j) {
        int idx = j * 256 + tid;
        int kch = idx >> 7, row = idx & 127;
        GLD_LDS(base + (size_t)(t0 + row) * K + k0 + kch * 8, lds + idx * 8);
    }
}
// fragment read: row R, k-offset quad*8 within the staged 32-chunk
__device__ __forceinline__ v8s frag(const short* lds, int R, int quad) {
    return *(const v8s*)(lds + ((quad << 7) + R) * 8);
}

// ---------------- dtype detection (fp32 vs bf16 storage) ----------------
__global__ void detect_kernel(const unsigned short* __restrict__ probe,
                              int nshorts, int* __restrict__ cnt) {
    int i = blockIdx.x * 256 + threadIdx.x;
    if (i < nshorts) {
        int e = (probe[i] >> 7) & 0xFF;
        if (e >= 140) atomicAdd(cnt, 1);
    }
}

// fused conversion of all float inputs into bf16 ws copies (4 elems/thread)
#define NCVT 9
struct CvtArgs {
    const void* src[NCVT];
    bf16* dst[NCVT];
    int n4[NCVT];
    int n[NCVT];
};
__global__ void cvt_all_kernel(CvtArgs args, const int* __restrict__ flag) {
    int i = blockIdx.x * 256 + threadIdx.x;
    int f = (*flag) > 8;
#pragma unroll
    for (int s = 0; s < NCVT; ++s) {
        int ns4 = args.n4[s];
        if (i < ns4) {
            int ns = args.n[s];
            int base = i * 4;
            bf16* dst = args.dst[s];
            if (f) {
                const float* sp = (const float*)args.src[s];
                if (base + 3 < ns) {
                    float4 v = *(const float4*)(sp + base);
                    ushort4 pk = { f2bfbits(v.x), f2bfbits(v.y),
                                   f2bfbits(v.z), f2bfbits(v.w) };
                    *(ushort4*)(dst + base) = pk;
                } else {
                    for (int j = 0; j < 4 && base + j < ns; ++j)
                        dst[base + j] = __float2bfloat16(sp[base + j]);
                }
            } else {
                const bf16* sp = (const bf16*)args.src[s];
                if (base + 3 < ns) {
                    *(ushort4*)(dst + base) = *(const ushort4*)(sp + base);
                } else {
                    for (int j = 0; j < 4 && base + j < ns; ++j)
                        dst[base + j] = sp[base + j];
                }
            }
            return;
        }
        i -= ns4;
    }
}

// ---------------- setup kernels ----------------

__global__ void count_kernel(const int* __restrict__ idx, int* __restrict__ cnt, int n) {
    int i = blockIdx.x * 256 + threadIdx.x;
    if (i < n) atomicAdd(&cnt[idx[i]], 1);
}

// fused: exclusive scan of deg (shfl block-scan) + gptr binary search
__global__ void scan_gptr_kernel(const int* __restrict__ cnt, int* __restrict__ ptr,
                                 const int* __restrict__ gid, int* __restrict__ gptr) {
    int tid = threadIdx.x;
    if (tid <= NGRAPH) {
        int lo = 0, hi = N_NODES;
        while (lo < hi) {
            int mid = (lo + hi) >> 1;
            if (gid[mid] < tid) lo = mid + 1; else hi = mid;
        }
        gptr[tid] = lo;
    }
    const int chunk = (N_NODES + 255) / 256;
    int b = tid * chunk, e = min(b + chunk, N_NODES);
    int loc = 0;
    for (int i = b; i < e; ++i) loc += cnt[i];
    int lane = tid & 63, wv = tid >> 6;
    int v = loc;
#pragma unroll
    for (int o = 1; o < 64; o <<= 1) {
        int t = __shfl_up(v, o);
        if (lane >= o) v += t;
    }
    __shared__ int wsum[4];
    if (lane == 63) wsum[wv] = v;
    __syncthreads();
    int wo = 0;
    for (int j = 0; j < wv; ++j) wo += wsum[j];
    int run = wo + v - loc;
    if (tid == 255) ptr[N_NODES] = wsum[0] + wsum[1] + wsum[2] + wsum[3];
    for (int i = b; i < e; ++i) { ptr[i] = run; run += cnt[i]; }
}

__global__ void fill_kernel(const int* __restrict__ src, const int* __restrict__ dst,
                            const int* __restrict__ rp, int* __restrict__ cursor,
                            int* __restrict__ esrc, int* __restrict__ edst) {
    int e = blockIdx.x * 256 + threadIdx.x;
    if (e < N_EDGES) {
        int d = dst[e];
        int pos = rp[d] + atomicAdd(&cursor[d], 1);
        esrc[pos] = src[e];
        edst[pos] = d;
    }
}

__global__ void sentinel_kernel(bf16* out, int n) {
    int i = blockIdx.x * 256 + threadIdx.x;
    if (i < n) out[i] = __float2bfloat16(2.0f);
}

// ---------------- fc GEMM + fused scores ------------------------------------
// C[M,384] = A[M,128] * B[384,128]^T, head-interleaved C write + per-head
// attention scores. grid (ceil(M/128), 3); blockIdx.y == head (128 cols).
__global__ __launch_bounds__(256) void gemm_fc(
    const bf16* __restrict__ A, const bf16* __restrict__ B,
    bf16* __restrict__ C, int M,
    const bf16* __restrict__ ans, const bf16* __restrict__ and_,
    float* __restrict__ s_ns, float* __restrict__ s_nd)
{
    __shared__ short lsA[4096];
    __shared__ short lsB[4096];
    const int tid  = threadIdx.x;
    const int wave = tid >> 6;
    const int lane = tid & 63;
    const int quad = lane >> 4;
    const int r16  = lane & 15;
    const int m0 = blockIdx.x * 128;
    const int n0 = blockIdx.y * 128;
    const int N = HEADS * DIM, K = DIM;
    const short* As = (const short*)A;
    const short* Bs = (const short*)B;

    v4f acc0[8], acc1[8];
#pragma unroll
    for (int t = 0; t < 8; ++t) {
        acc0[t] = (v4f){0.f, 0.f, 0.f, 0.f};
        acc1[t] = (v4f){0.f, 0.f, 0.f, 0.f};
    }
    for (int k0 = 0; k0 < K; k0 += 32) {
        stage_tile(As, m0, K, k0, lsA, tid);
        stage_tile(Bs, n0, K, k0, lsB, tid);
        __syncthreads();
        v8s a0 = frag(lsA, wave * 32 + r16, quad);
        v8s a1 = frag(lsA, wave * 32 + 16 + r16, quad);
#pragma unroll
        for (int t = 0; t < 8; ++t) {
            v8s b = frag(lsB, t * 16 + r16, quad);
            acc0[t] = __builtin_amdgcn_mfma_f32_16x16x32_bf16(a0, b, acc0[t], 0, 0, 0);
            acc1[t] = __builtin_amdgcn_mfma_f32_16x16x32_bf16(a1, b, acc1[t], 0, 0, 0);
        }
        __syncthreads();
    }
    const int mb = m0 + wave * 32;
    const int head = blockIdx.y;
#pragma unroll
    for (int t = 0; t < 8; ++t) {
        const int n = n0 + t * 16 + r16;
        const int d = n & 127;
        const size_t cix = (size_t)((d >> 1) * 6 + head * 2 + (d & 1));
#pragma unroll
        for (int mt = 0; mt < 2; ++mt) {
#pragma unroll
            for (int reg = 0; reg < 4; ++reg) {
                const int m = mb + mt * 16 + quad * 4 + reg;
                if (m >= M) continue;
                float v = (mt == 0 ? acc0[t][reg] : acc1[t][reg]);
                C[(size_t)m * N + cix] = __float2bfloat16(v);
            }
        }
    }
    float ansv[8], andv[8];
#pragma unroll
    for (int t = 0; t < 8; ++t) {
        int dcol = t * 16 + r16;
        ansv[t] = __bfloat162float(ans[head * 128 + dcol]);
        andv[t] = __bfloat162float(and_[head * 128 + dcol]);
    }
#pragma unroll
    for (int mt = 0; mt < 2; ++mt) {
#pragma unroll
        for (int reg = 0; reg < 4; ++reg) {
            float pns = 0.f, pnd = 0.f;
#pragma unroll
            for (int t = 0; t < 8; ++t) {
                float v = (mt == 0 ? acc0[t][reg] : acc1[t][reg]);
                pns += v * ansv[t];
                pnd += v * andv[t];
            }
#pragma unroll
            for (int o = 1; o < 16; o <<= 1) {
                pns += __shfl_xor(pns, o);
                pnd += __shfl_xor(pnd, o);
            }
            int m = mb + mt * 16 + quad * 4 + reg;
            if (r16 == 0 && m < M) {
                s_ns[m * 3 + head] = pns;
                s_nd[m * 3 + head] = pnd;
            }
        }
    }
}

// ---------------- trans GEMM + fused gate MLP -------------------------------
// fout[M,128] = agg[M,384] @ ctw^T + ctb (+relu) + resid; then, from the
// in-register/LDS tile: gateb[m] = sum_n relu(fout_row . p1w_n + p1b_n)*p2w_n.
// grid (ceil(M/128), 1). No atomics; gateb plain-stored.
__global__ __launch_bounds__(256) void gemm_tg(
    const bf16* __restrict__ A, const bf16* __restrict__ B,
    bf16* __restrict__ C, int M,
    const bf16* __restrict__ bias, const bf16* __restrict__ resid,
    int do_relu,
    const bf16* __restrict__ p1w, const bf16* __restrict__ p1b,
    const bf16* __restrict__ p2w, float* __restrict__ gateb)
{
    __shared__ short lsA[4096];
    __shared__ short lsB[4096];
    __shared__ short lsO[16384];   // 128x128 bf16 fout tile, granule layout
    const int tid  = threadIdx.x;
    const int wave = tid >> 6;
    const int lane = tid & 63;
    const int quad = lane >> 4;
    const int r16  = lane & 15;
    const int m0 = blockIdx.x * 128;
    const int K1 = HEADS * DIM;    // 384
    const short* As = (const short*)A;
    const short* Bs = (const short*)B;

    v4f acc0[8], acc1[8];
#pragma unroll
    for (int t = 0; t < 8; ++t) {
        acc0[t] = (v4f){0.f, 0.f, 0.f, 0.f};
        acc1[t] = (v4f){0.f, 0.f, 0.f, 0.f};
    }
    for (int k0 = 0; k0 < K1; k0 += 32) {
        stage_tile(As, m0, K1, k0, lsA, tid);
        stage_tile(Bs, 0, K1, k0, lsB, tid);
        __syncthreads();
        v8s a0 = frag(lsA, wave * 32 + r16, quad);
        v8s a1 = frag(lsA, wave * 32 + 16 + r16, quad);
#pragma unroll
        for (int t = 0; t < 8; ++t) {
            v8s b = frag(lsB, t * 16 + r16, quad);
            acc0[t] = __builtin_amdgcn_mfma_f32_16x16x32_bf16(a0, b, acc0[t], 0, 0, 0);
            acc1[t] = __builtin_amdgcn_mfma_f32_16x16x32_bf16(a1, b, acc1[t], 0, 0, 0);
        }
        __syncthreads();
    }
    // epilogue 1: bias+relu+resid -> write fout AND stash tile to lsO
#pragma unroll
    for (int t = 0; t < 8; ++t) {
        const int n = t * 16 + r16;
        const float bb = __bfloat162float(bias[n]);
#pragma unroll
        for (int mt = 0; mt < 2; ++mt) {
#pragma unroll
            for (int reg = 0; reg < 4; ++reg) {
                const int rloc = wave * 32 + mt * 16 + quad * 4 + reg;
                const int m = m0 + rloc;
                float v = (mt == 0 ? acc0[t][reg] : acc1[t][reg]) + bb;
                if (do_relu) v = fmaxf(v, 0.f);
                if (m < M) {
                    v += __bfloat162float(resid[(size_t)m * DIM + n]);
                    C[(size_t)m * DIM + n] = __float2bfloat16(v);
                }
                // granule layout: (kchunk=n>>3)*128 + row, sub-offset n&7
                lsO[(((n >> 3) << 7) + rloc) * 8 + (n & 7)] = f2bfbits(v);
            }
        }
    }
    __syncthreads();
    // GEMM2: [128 x 256] = lsO[128x128] @ p1w[256,128]^T, fused gate epilogue
    v4f g0[16], g1[16];
#pragma unroll
    for (int t = 0; t < 16; ++t) {
        g0[t] = (v4f){0.f, 0.f, 0.f, 0.f};
        g1[t] = (v4f){0.f, 0.f, 0.f, 0.f};
    }
    const short* Pw = (const short*)p1w;
    for (int k0 = 0; k0 < 128; k0 += 32) {
        const int kb = k0 >> 3;
        v8s a0 = *(const v8s*)(lsO + (((kb + quad) << 7) + wave * 32 + r16) * 8);
        v8s a1 = *(const v8s*)(lsO + (((kb + quad) << 7) + wave * 32 + 16 + r16) * 8);
#pragma unroll
        for (int t = 0; t < 16; ++t) {
            v8s b = *(const v8s*)(Pw + (size_t)(t * 16 + r16) * 128 + k0 + quad * 8);
            g0[t] = __builtin_amdgcn_mfma_f32_16x16x32_bf16(a0, b, g0[t], 0, 0, 0);
            g1[t] = __builtin_amdgcn_mfma_f32_16x16x32_bf16(a1, b, g1[t], 0, 0, 0);
        }
    }
    float p1bv[16], p2wv[16];
#pragma unroll
    for (int t = 0; t < 16; ++t) {
        int n = t * 16 + r16;
        p1bv[t] = __bfloat162float(p1b[n]);
        p2wv[t] = __bfloat162float(p2w[n]);
    }
#pragma unroll
    for (int mt = 0; mt < 2; ++mt) {
#pragma unroll
        for (int reg = 0; reg < 4; ++reg) {
            float g = 0.f;
#pragma unroll
            for (int t = 0; t < 16; ++t) {
                float v = (mt == 0 ? g0[t][reg] : g1[t][reg]);
                g += fmaxf(v + p1bv[t], 0.f) * p2wv[t];
            }
#pragma unroll
            for (int o = 1; o < 16; o <<= 1) g += __shfl_xor(g, o);
            int m = m0 + wave * 32 + mt * 16 + quad * 4 + reg;
            if (r16 == 0 && m < M) gateb[m] = g;
        }
    }
}

// ---------------- per-edge softmax numerators (maxless, CSR order) ----------
__global__ void pedge_kernel(const int* __restrict__ esrc,
                             const int* __restrict__ edst,
                             const float* __restrict__ s_ns,
                             const float* __restrict__ s_nd,
                             float* __restrict__ pedge) {
    int i = blockIdx.x * 256 + threadIdx.x;
    if (i >= N_EDGES) return;
    int s = esrc[i], d = edst[i];
    pedge[i * 3 + 0] = __expf(leaky(s_ns[s * 3 + 0] + s_nd[d * 3 + 0]));
    pedge[i * 3 + 1] = __expf(leaky(s_ns[s * 3 + 1] + s_nd[d * 3 + 1]));
    pedge[i * 3 + 2] = __expf(leaky(s_ns[s * 3 + 2] + s_nd[d * 3 + 2]));
}

// ---------------- aggregate: one WAVE per dst node, pure gather loop --------
__global__ __launch_bounds__(256) void agg_kernel(
    const unsigned* __restrict__ h2, const int* __restrict__ rp,
    const int* __restrict__ esrc, const float* __restrict__ pedge,
    bf16* __restrict__ agg)
{
    const int node = blockIdx.x * 4 + (threadIdx.x >> 6);
    if (node >= N_NODES) return;
    const int lane = threadIdx.x & 63;
    const int beg = rp[node], end = rp[node + 1];
    const int cnt = end - beg;
    unsigned* outp = (unsigned*)(agg + (size_t)node * (HEADS * DIM));
    if (cnt <= 0) {
        outp[lane] = 0u; outp[64 + lane] = 0u; outp[128 + lane] = 0u;
        return;
    }
    float ss0 = 0.f, ss1 = 0.f, ss2 = 0.f;
    float a0 = 0.f, a1 = 0.f, a2 = 0.f, a3 = 0.f, a4 = 0.f, a5 = 0.f;
    const float* pp = pedge + (size_t)beg * 3;
    const int* ep = esrc + beg;
#pragma unroll 4
    for (int j = 0; j < cnt; ++j) {
        int s = ep[j];
        float p0 = pp[j * 3 + 0];
        float p1 = pp[j * 3 + 1];
        float p2 = pp[j * 3 + 2];
        ss0 += p0; ss1 += p1; ss2 += p2;
        v3u w = *(const v3u*)(h2 + (size_t)s * 192 + lane * 3);
        a0 += p0 * lo2f(w.x); a1 += p0 * hi2f(w.x);
        a2 += p1 * lo2f(w.y); a3 += p1 * hi2f(w.y);
        a4 += p2 * lo2f(w.z); a5 += p2 * hi2f(w.z);
    }
    float i0 = 1.f / ss0, i1 = 1.f / ss1, i2 = 1.f / ss2;
    outp[lane]       = packbf(a0 * i0, a1 * i0);
    outp[64 + lane]  = packbf(a2 * i1, a3 * i1);
    outp[128 + lane] = packbf(a4 * i2, a5 * i2);
}

// ---------------- pooled accumulation w/ inline stats: 8 blocks/graph -------
__global__ __launch_bounds__(256) void pool_acc(
    const bf16* __restrict__ feat, const float* __restrict__ gate,
    const int* __restrict__ gptr, float* __restrict__ out_acc)
{
    const int g = blockIdx.x;
    const int chunk = blockIdx.y;
    const int tid = threadIdx.x;
    const int beg = gptr[g], end = gptr[g + 1];
    if (beg >= end) return;
    __shared__ float red[4];
    float m = -1e30f;
    for (int i = beg + tid; i < end; i += 256) m = fmaxf(m, gate[i]);
#pragma unroll
    for (int o = 32; o > 0; o >>= 1) m = fmaxf(m, __shfl_xor(m, o));
    if ((tid & 63) == 0) red[tid >> 6] = m;
    __syncthreads();
    m = fmaxf(fmaxf(red[0], red[1]), fmaxf(red[2], red[3]));
    __syncthreads();
    float s = 0.f;
    for (int i = beg + tid; i < end; i += 256) s += __expf(gate[i] - m);
#pragma unroll
    for (int o = 32; o > 0; o >>= 1) s += __shfl_xor(s, o);
    if ((tid & 63) == 0) red[tid >> 6] = s;
    __syncthreads();
    float inv = 1.f / (red[0] + red[1] + red[2] + red[3]);
    const int p = tid >> 7;
    const int c = tid & 127;
    float acc = 0.f;
    for (int i = beg + chunk * 2 + p; i < end; i += 16) {
        float w = __expf(gate[i] - m);
        acc += w * __bfloat162float(feat[(size_t)i * DIM + c]);
    }
    acc *= inv;
    atomicAdd(&out_acc[g * DIM + c], acc);
}

__global__ void writeout_kernel(const float* __restrict__ out_acc,
                                void* __restrict__ out, const int* __restrict__ flag) {
    int i = blockIdx.x * 256 + threadIdx.x;
    if (i < NGRAPH * DIM) {
        float v = out_acc[i] * (1.f / 3.f);
        if ((*flag) > 8) ((float*)out)[i] = v;
        else ((bf16*)out)[i] = __float2bfloat16(v);
    }
}

// ---------------- host launcher ----------------
extern "C" void kernel_launch(void* const* d_in, const int* in_sizes, int n_in,
                              void* d_out, int out_size, void* d_ws, size_t ws_size,
                              hipStream_t stream)
{
    const void* feat_in = d_in[0];
    const int* src = (const int*)d_in[1];
    const int* dst = (const int*)d_in[2];
    const int* gid = (const int*)d_in[3];

    char* base = (char*)d_ws;
    size_t off = 0;
    auto carve = [&](size_t bytes) -> void* {
        void* p = base + off;
        off = (off + bytes + 255) & ~(size_t)255;
        return p;
    };
    // zeroed region: dflag | deg | cursor | out_acc -> ONE memset
    size_t zbytes = 256 + sizeof(int) * 2 * N_NODES + sizeof(float) * NGRAPH * DIM;
    char* zreg  = (char*)carve(zbytes);
    int* dflag  = (int*)zreg;
    int* deg    = (int*)(zreg + 256);
    int* cursor = deg + N_NODES;
    float* out_acc = (float*)(cursor + N_NODES);
    float* gateb3 = (float*)carve(sizeof(float) * LAYERS * N_NODES); // plain-stored
    int* rp     = (int*)carve(sizeof(int) * (N_NODES + 1));
    int* gptr   = (int*)carve(sizeof(int) * (NGRAPH + 1));
    int* esrc   = (int*)carve(sizeof(int) * N_EDGES);
    int* edst   = (int*)carve(sizeof(int) * N_EDGES);
    float* pedge = (float*)carve(sizeof(float) * N_EDGES * 3);
    float* s_ns = (float*)carve(sizeof(float) * N_NODES * HEADS);
    float* s_nd = (float*)carve(sizeof(float) * N_NODES * HEADS);
    bf16* featA = (bf16*)carve(sizeof(bf16) * N_NODES * DIM);
    bf16* featB = (bf16*)carve(sizeof(bf16) * N_NODES * DIM);
    bf16* cfc   = (bf16*)carve(sizeof(bf16) * LAYERS * HEADS * DIM * DIM);
    bf16* cans  = (bf16*)carve(sizeof(bf16) * LAYERS * HEADS * DIM);
    bf16* cand  = (bf16*)carve(sizeof(bf16) * LAYERS * HEADS * DIM);
    bf16* ctw   = (bf16*)carve(sizeof(bf16) * LAYERS * DIM * HEADS * DIM);
    bf16* ctb   = (bf16*)carve(sizeof(bf16) * LAYERS * DIM);
    bf16* cp1w  = (bf16*)carve(sizeof(bf16) * LAYERS * 2 * DIM * DIM);
    bf16* cp1b  = (bf16*)carve(sizeof(bf16) * LAYERS * 2 * DIM);
    bf16* cp2w  = (bf16*)carve(sizeof(bf16) * LAYERS * 2 * DIM);
    bf16* hbuf   = (bf16*)carve(sizeof(bf16) * N_NODES * HEADS * DIM);
    bf16* aggbuf = (bf16*)carve(sizeof(bf16) * N_NODES * HEADS * DIM);
    carve(131072);   // pad: GEMM A-tile tail overreads (96 rows x 384 x 2B)

    if (off > ws_size) {
        sentinel_kernel<<<(out_size + 255) / 256, 256, 0, stream>>>(
            (bf16*)d_out, out_size);
        return;
    }

    hipMemsetAsync(zreg, 0, zbytes, stream);
    detect_kernel<<<128, 256, 0, stream>>>(
        (const unsigned short*)feat_in, 32768, dflag);

    CvtArgs ca;
    const int cvt_n[NCVT] = {
        N_NODES * DIM, LAYERS * HEADS * DIM * DIM, LAYERS * HEADS * DIM,
        LAYERS * HEADS * DIM, LAYERS * DIM * HEADS * DIM, LAYERS * DIM,
        LAYERS * 2 * DIM * DIM, LAYERS * 2 * DIM, LAYERS * 2 * DIM };
    bf16* cvt_dst[NCVT] = { featA, cfc, cans, cand, ctw, ctb, cp1w, cp1b, cp2w };
    const int cvt_src_idx[NCVT] = { 0, 4, 5, 6, 7, 8, 9, 10, 11 };
    int total4 = 0;
    for (int s = 0; s < NCVT; ++s) {
        ca.src[s] = d_in[cvt_src_idx[s]];
        ca.dst[s] = cvt_dst[s];
        ca.n[s] = cvt_n[s];
        ca.n4[s] = (cvt_n[s] + 3) / 4;
        total4 += ca.n4[s];
    }
    cvt_all_kernel<<<(total4 + 255) / 256, 256, 0, stream>>>(ca, dflag);

    count_kernel<<<(N_EDGES + 255) / 256, 256, 0, stream>>>(dst, deg, N_EDGES);
    scan_gptr_kernel<<<1, 256, 0, stream>>>(deg, rp, gid, gptr);
    fill_kernel<<<(N_EDGES + 255) / 256, 256, 0, stream>>>(
        src, dst, rp, cursor, esrc, edst);

    const int MBLK = (N_NODES + 127) / 128;   // 157
    bf16* fin = featA;
    bf16* fout = featB;
    for (int d = 0; d < LAYERS; ++d) {
        float* gateb = gateb3 + (size_t)d * N_NODES;
        gemm_fc<<<dim3(MBLK, 3), 256, 0, stream>>>(
            fin, cfc + (size_t)d * HEADS * DIM * DIM, hbuf, N_NODES,
            cans + (size_t)d * HEADS * DIM, cand + (size_t)d * HEADS * DIM,
            s_ns, s_nd);
        pedge_kernel<<<(N_EDGES + 255) / 256, 256, 0, stream>>>(
            esrc, edst, s_ns, s_nd, pedge);
        agg_kernel<<<(N_NODES + 3) / 4, 256, 0, stream>>>(
            (const unsigned*)hbuf, rp, esrc, pedge, aggbuf);
        gemm_tg<<<dim3(MBLK, 1), 256, 0, stream>>>(
            aggbuf, ctw + (size_t)d * DIM * HEADS * DIM, fout, N_NODES,
            ctb + (size_t)d * DIM, fin, (d < LAYERS - 1) ? 1 : 0,
            cp1w + (size_t)d * 2 * DIM * DIM, cp1b + (size_t)d * 2 * DIM,
            cp2w + (size_t)d * 2 * DIM, gateb);
        pool_acc<<<dim3(NGRAPH, 8), 256, 0, stream>>>(
            fout, gateb, gptr, out_acc);
        bf16* t = fin; fin = fout; fout = t;
    }
    writeout_kernel<<<(NGRAPH * DIM + 255) / 256, 256, 0, stream>>>(
        out_acc, d_out, dflag);
}

// Round 12
// 478.775 us; speedup vs baseline: 1.0166x; 1.0166x over previous
//
#include <hip/hip_runtime.h>
#include <hip/hip_bf16.h>

#define N_NODES 20000
#define N_EDGES 320000
#define DIM 128
#define HEADS 3
#define LAYERS 3
#define NGRAPH 64
#define NEG_SLOPE 0.2f

typedef const __hip_bfloat16* bfp;
typedef __hip_bfloat16 bf16;
typedef short v8s __attribute__((ext_vector_type(8)));
typedef float v4f __attribute__((ext_vector_type(4)));
typedef unsigned v3u __attribute__((ext_vector_type(3)));

#define GLD_LDS(gp, lp) \
    __builtin_amdgcn_global_load_lds( \
        (const __attribute__((address_space(1))) void*)(gp), \
        (__attribute__((address_space(3))) void*)(lp), 16, 0, 0)

__device__ __forceinline__ float b2f(unsigned short u) {
    return __uint_as_float(((unsigned)u) << 16);
}
__device__ __forceinline__ float lo2f(unsigned u) { return __uint_as_float(u << 16); }
__device__ __forceinline__ float hi2f(unsigned u) { return __uint_as_float(u & 0xffff0000u); }
__device__ __forceinline__ float leaky(float z) {
    return z >= 0.f ? z : NEG_SLOPE * z;
}
__device__ __forceinline__ unsigned packbf(float a, float b) {
    bf16 x = __float2bfloat16(a), y = __float2bfloat16(b);
    return (unsigned)*(unsigned short*)&x | ((unsigned)*(unsigned short*)&y << 16);
}
__device__ __forceinline__ unsigned short f2bfbits(float v) {
    bf16 x = __float2bfloat16(v);
    return *(unsigned short*)&x;
}

// Stage a 128x32 bf16 tile into LDS in GRANULE layout: granule g =
// kchunk*128 + row (kchunk = k/8), LDS shorts addr = g*8. Fragment reads then
// have 4-dword row stride -> 2-way bank aliasing only (free on CDNA4).
__device__ __forceinline__ void stage_tile(const short* base, int t0, int K,
                                           int k0, short* lds, int tid) {
#pragma unroll
    for (int j = 0; j < 2; ++j) {
        int idx = j * 256 + tid;
        int kch = idx >> 7, row = idx & 127;
        GLD_LDS(base + (size_t)(t0 + row) * K + k0 + kch * 8, lds + idx * 8);
    }
}
__device__ __forceinline__ v8s frag(const short* lds, int R, int quad) {
    return *(const v8s*)(lds + ((quad << 7) + R) * 8);
}

// ---------------- dtype detection (fp32 vs bf16 storage) ----------------
__global__ void detect_kernel(const unsigned short* __restrict__ probe,
                              int nshorts, int* __restrict__ cnt) {
    int i = blockIdx.x * 256 + threadIdx.x;
    if (i < nshorts) {
        int e = (probe[i] >> 7) & 0xFF;
        if (e >= 140) atomicAdd(cnt, 1);
    }
}

// fused conversion of all float inputs into bf16 ws copies (4 elems/thread)
#define NCVT 9
struct CvtArgs {
    const void* src[NCVT];
    bf16* dst[NCVT];
    int n4[NCVT];
    int n[NCVT];
};
__global__ void cvt_all_kernel(CvtArgs args, const int* __restrict__ flag) {
    int i = blockIdx.x * 256 + threadIdx.x;
    int f = (*flag) > 8;
#pragma unroll
    for (int s = 0; s < NCVT; ++s) {
        int ns4 = args.n4[s];
        if (i < ns4) {
            int ns = args.n[s];
            int base = i * 4;
            bf16* dst = args.dst[s];
            if (f) {
                const float* sp = (const float*)args.src[s];
                if (base + 3 < ns) {
                    float4 v = *(const float4*)(sp + base);
                    ushort4 pk = { f2bfbits(v.x), f2bfbits(v.y),
                                   f2bfbits(v.z), f2bfbits(v.w) };
                    *(ushort4*)(dst + base) = pk;
                } else {
                    for (int j = 0; j < 4 && base + j < ns; ++j)
                        dst[base + j] = __float2bfloat16(sp[base + j]);
                }
            } else {
                const bf16* sp = (const bf16*)args.src[s];
                if (base + 3 < ns) {
                    *(ushort4*)(dst + base) = *(const ushort4*)(sp + base);
                } else {
                    for (int j = 0; j < 4 && base + j < ns; ++j)
                        dst[base + j] = sp[base + j];
                }
            }
            return;
        }
        i -= ns4;
    }
}

// ---------------- setup kernels ----------------

__global__ void count_kernel(const int* __restrict__ idx, int* __restrict__ cnt, int n) {
    int i = blockIdx.x * 256 + threadIdx.x;
    if (i < n) atomicAdd(&cnt[idx[i]], 1);
}

// fused: exclusive scan of deg (shfl block-scan) + gptr binary search
__global__ void scan_gptr_kernel(const int* __restrict__ cnt, int* __restrict__ ptr,
                                 const int* __restrict__ gid, int* __restrict__ gptr) {
    int tid = threadIdx.x;
    if (tid <= NGRAPH) {
        int lo = 0, hi = N_NODES;
        while (lo < hi) {
            int mid = (lo + hi) >> 1;
            if (gid[mid] < tid) lo = mid + 1; else hi = mid;
        }
        gptr[tid] = lo;
    }
    const int chunk = (N_NODES + 255) / 256;
    int b = tid * chunk, e = min(b + chunk, N_NODES);
    int loc = 0;
    for (int i = b; i < e; ++i) loc += cnt[i];
    int lane = tid & 63, wv = tid >> 6;
    int v = loc;
#pragma unroll
    for (int o = 1; o < 64; o <<= 1) {
        int t = __shfl_up(v, o);
        if (lane >= o) v += t;
    }
    __shared__ int wsum[4];
    if (lane == 63) wsum[wv] = v;
    __syncthreads();
    int wo = 0;
    for (int j = 0; j < wv; ++j) wo += wsum[j];
    int run = wo + v - loc;
    if (tid == 255) ptr[N_NODES] = wsum[0] + wsum[1] + wsum[2] + wsum[3];
    for (int i = b; i < e; ++i) { ptr[i] = run; run += cnt[i]; }
}

__global__ void fill_kernel(const int* __restrict__ src, const int* __restrict__ dst,
                            const int* __restrict__ rp, int* __restrict__ cursor,
                            int* __restrict__ esrc, int* __restrict__ edst) {
    int e = blockIdx.x * 256 + threadIdx.x;
    if (e < N_EDGES) {
        int d = dst[e];
        int pos = rp[d] + atomicAdd(&cursor[d], 1);
        esrc[pos] = src[e];
        edst[pos] = d;
    }
}

__global__ void sentinel_kernel(bf16* out, int n) {
    int i = blockIdx.x * 256 + threadIdx.x;
    if (i < n) out[i] = __float2bfloat16(2.0f);
}

// ---------------- MFMA GEMM, LDS-staged, granule layout ---------------------
// C[M,N] = A[M,K] * B[N,K]^T, bf16 in, fp32 acc. Block tile 128x128, 4 waves.
// MODE 0: plain C (+bias/relu/resid)
// MODE 1: head-interleaved C + fused scores (N=384, blockIdx.y == head)
// MODE 2: no C; fused gate layer-2: relu(acc+bias).p2w -> atomicAdd gateb
template <int MODE>
__global__ __launch_bounds__(256) void gemm_mfma(
    const bf16* __restrict__ A, const bf16* __restrict__ B,
    bf16* __restrict__ C, int M, int N, int K,
    const bf16* __restrict__ bias, const bf16* __restrict__ resid,
    int do_relu,
    const bf16* __restrict__ ans, const bf16* __restrict__ and_,
    float* __restrict__ s_ns, float* __restrict__ s_nd,
    const bf16* __restrict__ p2w, float* __restrict__ gateb)
{
    __shared__ short lsA[4096];
    __shared__ short lsB[4096];
    const int tid  = threadIdx.x;
    const int wave = tid >> 6;
    const int lane = tid & 63;
    const int quad = lane >> 4;
    const int r16  = lane & 15;
    const int m0 = blockIdx.x * 128;
    const int n0 = blockIdx.y * 128;
    const short* As = (const short*)A;
    const short* Bs = (const short*)B;

    v4f acc0[8], acc1[8];
#pragma unroll
    for (int t = 0; t < 8; ++t) {
        acc0[t] = (v4f){0.f, 0.f, 0.f, 0.f};
        acc1[t] = (v4f){0.f, 0.f, 0.f, 0.f};
    }
    for (int k0 = 0; k0 < K; k0 += 32) {
        stage_tile(As, m0, K, k0, lsA, tid);
        stage_tile(Bs, n0, K, k0, lsB, tid);
        __syncthreads();
        v8s a0 = frag(lsA, wave * 32 + r16, quad);
        v8s a1 = frag(lsA, wave * 32 + 16 + r16, quad);
#pragma unroll
        for (int t = 0; t < 8; ++t) {
            v8s b = frag(lsB, t * 16 + r16, quad);
            acc0[t] = __builtin_amdgcn_mfma_f32_16x16x32_bf16(a0, b, acc0[t], 0, 0, 0);
            acc1[t] = __builtin_amdgcn_mfma_f32_16x16x32_bf16(a1, b, acc1[t], 0, 0, 0);
        }
        __syncthreads();
    }

    const int mb = m0 + wave * 32;

    if (MODE == 2) {
        float pwv[8], bbv[8];
#pragma unroll
        for (int t = 0; t < 8; ++t) {
            int n = n0 + t * 16 + r16;
            pwv[t] = __bfloat162float(p2w[n]);
            bbv[t] = __bfloat162float(bias[n]);
        }
#pragma unroll
        for (int mt = 0; mt < 2; ++mt) {
#pragma unroll
            for (int reg = 0; reg < 4; ++reg) {
                float g = 0.f;
#pragma unroll
                for (int t = 0; t < 8; ++t) {
                    float v = (mt == 0 ? acc0[t][reg] : acc1[t][reg]);
                    g += fmaxf(v + bbv[t], 0.f) * pwv[t];
                }
#pragma unroll
                for (int o = 1; o < 16; o <<= 1) g += __shfl_xor(g, o);
                int m = mb + mt * 16 + quad * 4 + reg;
                if (r16 == 0 && m < M) atomicAdd(&gateb[m], g);
            }
        }
        return;
    }

#pragma unroll
    for (int t = 0; t < 8; ++t) {
        const int n = n0 + t * 16 + r16;
        float bb = bias ? __bfloat162float(bias[n]) : 0.f;
#pragma unroll
        for (int mt = 0; mt < 2; ++mt) {
#pragma unroll
            for (int reg = 0; reg < 4; ++reg) {
                const int m = mb + mt * 16 + quad * 4 + reg;
                if (m >= M) continue;
                float v = (mt == 0 ? acc0[t][reg] : acc1[t][reg]);
                if (bias) {
                    v += bb;
                    if (do_relu) v = fmaxf(v, 0.f);
                }
                if (resid) v += __bfloat162float(resid[(size_t)m * N + n]);
                size_t idx;
                if (MODE == 1) {
                    int d = n & 127, head = n >> 7;
                    idx = (size_t)m * N + (size_t)((d >> 1) * 6 + head * 2 + (d & 1));
                } else {
                    idx = (size_t)m * N + n;
                }
                C[idx] = __float2bfloat16(v);
            }
        }
    }

    if (MODE == 1) {
        const int head = blockIdx.y;
        float ansv[8], andv[8];
#pragma unroll
        for (int t = 0; t < 8; ++t) {
            int dcol = t * 16 + r16;
            ansv[t] = __bfloat162float(ans[head * 128 + dcol]);
            andv[t] = __bfloat162float(and_[head * 128 + dcol]);
        }
#pragma unroll
        for (int mt = 0; mt < 2; ++mt) {
#pragma unroll
            for (int reg = 0; reg < 4; ++reg) {
                float pns = 0.f, pnd = 0.f;
#pragma unroll
                for (int t = 0; t < 8; ++t) {
                    float v = (mt == 0 ? acc0[t][reg] : acc1[t][reg]);
                    pns += v * ansv[t];
                    pnd += v * andv[t];
                }
#pragma unroll
                for (int o = 1; o < 16; o <<= 1) {
                    pns += __shfl_xor(pns, o);
                    pnd += __shfl_xor(pnd, o);
                }
                int m = mb + mt * 16 + quad * 4 + reg;
                if (r16 == 0 && m < M) {
                    s_ns[m * 3 + head] = pns;
                    s_nd[m * 3 + head] = pnd;
                }
            }
        }
    }
}

// ---------------- per-edge softmax numerators (maxless, CSR order) ----------
__global__ void pedge_kernel(const int* __restrict__ esrc,
                             const int* __restrict__ edst,
                             const float* __restrict__ s_ns,
                             const float* __restrict__ s_nd,
                             float* __restrict__ pedge) {
    int i = blockIdx.x * 256 + threadIdx.x;
    if (i >= N_EDGES) return;
    int s = esrc[i], d = edst[i];
    pedge[i * 3 + 0] = __expf(leaky(s_ns[s * 3 + 0] + s_nd[d * 3 + 0]));
    pedge[i * 3 + 1] = __expf(leaky(s_ns[s * 3 + 1] + s_nd[d * 3 + 1]));
    pedge[i * 3 + 2] = __expf(leaky(s_ns[s * 3 + 2] + s_nd[d * 3 + 2]));
}

// ---------------- aggregate: one WAVE per dst node, pure gather loop --------
__global__ __launch_bounds__(256) void agg_kernel(
    const unsigned* __restrict__ h2, const int* __restrict__ rp,
    const int* __restrict__ esrc, const float* __restrict__ pedge,
    bf16* __restrict__ agg)
{
    const int node = blockIdx.x * 4 + (threadIdx.x >> 6);
    if (node >= N_NODES) return;
    const int lane = threadIdx.x & 63;
    const int beg = rp[node], end = rp[node + 1];
    const int cnt = end - beg;
    unsigned* outp = (unsigned*)(agg + (size_t)node * (HEADS * DIM));
    if (cnt <= 0) {
        outp[lane] = 0u; outp[64 + lane] = 0u; outp[128 + lane] = 0u;
        return;
    }
    float ss0 = 0.f, ss1 = 0.f, ss2 = 0.f;
    float a0 = 0.f, a1 = 0.f, a2 = 0.f, a3 = 0.f, a4 = 0.f, a5 = 0.f;
    const float* pp = pedge + (size_t)beg * 3;
    const int* ep = esrc + beg;
#pragma unroll 4
    for (int j = 0; j < cnt; ++j) {
        int s = ep[j];
        float p0 = pp[j * 3 + 0];
        float p1 = pp[j * 3 + 1];
        float p2 = pp[j * 3 + 2];
        ss0 += p0; ss1 += p1; ss2 += p2;
        v3u w = *(const v3u*)(h2 + (size_t)s * 192 + lane * 3);
        a0 += p0 * lo2f(w.x); a1 += p0 * hi2f(w.x);
        a2 += p1 * lo2f(w.y); a3 += p1 * hi2f(w.y);
        a4 += p2 * lo2f(w.z); a5 += p2 * hi2f(w.z);
    }
    float i0 = 1.f / ss0, i1 = 1.f / ss1, i2 = 1.f / ss2;
    outp[lane]       = packbf(a0 * i0, a1 * i0);
    outp[64 + lane]  = packbf(a2 * i1, a3 * i1);
    outp[128 + lane] = packbf(a4 * i2, a5 * i2);
}

// ---------------- pooled accumulation w/ inline stats: 8 blocks/graph -------
__global__ __launch_bounds__(256) void pool_acc(
    const bf16* __restrict__ feat, const float* __restrict__ gate,
    const int* __restrict__ gptr, float* __restrict__ out_acc)
{
    const int g = blockIdx.x;
    const int chunk = blockIdx.y;
    const int tid = threadIdx.x;
    const int beg = gptr[g], end = gptr[g + 1];
    if (beg >= end) return;
    __shared__ float red[4];
    float m = -1e30f;
    for (int i = beg + tid; i < end; i += 256) m = fmaxf(m, gate[i]);
#pragma unroll
    for (int o = 32; o > 0; o >>= 1) m = fmaxf(m, __shfl_xor(m, o));
    if ((tid & 63) == 0) red[tid >> 6] = m;
    __syncthreads();
    m = fmaxf(fmaxf(red[0], red[1]), fmaxf(red[2], red[3]));
    __syncthreads();
    float s = 0.f;
    for (int i = beg + tid; i < end; i += 256) s += __expf(gate[i] - m);
#pragma unroll
    for (int o = 32; o > 0; o >>= 1) s += __shfl_xor(s, o);
    if ((tid & 63) == 0) red[tid >> 6] = s;
    __syncthreads();
    float inv = 1.f / (red[0] + red[1] + red[2] + red[3]);
    const int p = tid >> 7;
    const int c = tid & 127;
    float acc = 0.f;
    for (int i = beg + chunk * 2 + p; i < end; i += 16) {
        float w = __expf(gate[i] - m);
        acc += w * __bfloat162float(feat[(size_t)i * DIM + c]);
    }
    acc *= inv;
    atomicAdd(&out_acc[g * DIM + c], acc);
}

__global__ void writeout_kernel(const float* __restrict__ out_acc,
                                void* __restrict__ out, const int* __restrict__ flag) {
    int i = blockIdx.x * 256 + threadIdx.x;
    if (i < NGRAPH * DIM) {
        float v = out_acc[i] * (1.f / 3.f);
        if ((*flag) > 8) ((float*)out)[i] = v;
        else ((bf16*)out)[i] = __float2bfloat16(v);
    }
}

// ---------------- host launcher ----------------
extern "C" void kernel_launch(void* const* d_in, const int* in_sizes, int n_in,
                              void* d_out, int out_size, void* d_ws, size_t ws_size,
                              hipStream_t stream)
{
    const void* feat_in = d_in[0];
    const int* src = (const int*)d_in[1];
    const int* dst = (const int*)d_in[2];
    const int* gid = (const int*)d_in[3];

    char* base = (char*)d_ws;
    size_t off = 0;
    auto carve = [&](size_t bytes) -> void* {
        void* p = base + off;
        off = (off + bytes + 255) & ~(size_t)255;
        return p;
    };
    // zeroed region: dflag | deg | cursor | out_acc | gateb[3] -> ONE memset
    size_t zbytes = 256 + sizeof(int) * 2 * N_NODES + sizeof(float) * NGRAPH * DIM
                  + sizeof(float) * LAYERS * N_NODES;
    char* zreg  = (char*)carve(zbytes);
    int* dflag  = (int*)zreg;
    int* deg    = (int*)(zreg + 256);
    int* cursor = deg + N_NODES;
    float* out_acc = (float*)(cursor + N_NODES);
    float* gateb3  = out_acc + NGRAPH * DIM;
    int* rp     = (int*)carve(sizeof(int) * (N_NODES + 1));
    int* gptr   = (int*)carve(sizeof(int) * (NGRAPH + 1));
    int* esrc   = (int*)carve(sizeof(int) * N_EDGES);
    int* edst   = (int*)carve(sizeof(int) * N_EDGES);
    float* pedge = (float*)carve(sizeof(float) * N_EDGES * 3);
    float* s_ns = (float*)carve(sizeof(float) * N_NODES * HEADS);
    float* s_nd = (float*)carve(sizeof(float) * N_NODES * HEADS);
    bf16* featA = (bf16*)carve(sizeof(bf16) * N_NODES * DIM);
    bf16* featB = (bf16*)carve(sizeof(bf16) * N_NODES * DIM);
    bf16* cfc   = (bf16*)carve(sizeof(bf16) * LAYERS * HEADS * DIM * DIM);
    bf16* cans  = (bf16*)carve(sizeof(bf16) * LAYERS * HEADS * DIM);
    bf16* cand  = (bf16*)carve(sizeof(bf16) * LAYERS * HEADS * DIM);
    bf16* ctw   = (bf16*)carve(sizeof(bf16) * LAYERS * DIM * HEADS * DIM);
    bf16* ctb   = (bf16*)carve(sizeof(bf16) * LAYERS * DIM);
    bf16* cp1w  = (bf16*)carve(sizeof(bf16) * LAYERS * 2 * DIM * DIM);
    bf16* cp1b  = (bf16*)carve(sizeof(bf16) * LAYERS * 2 * DIM);
    bf16* cp2w  = (bf16*)carve(sizeof(bf16) * LAYERS * 2 * DIM);
    bf16* hbuf   = (bf16*)carve(sizeof(bf16) * N_NODES * HEADS * DIM);
    bf16* aggbuf = (bf16*)carve(sizeof(bf16) * N_NODES * HEADS * DIM);
    carve(131072);   // pad: GEMM A-tile tail overreads (96 rows x 384 x 2B)

    if (off > ws_size) {
        sentinel_kernel<<<(out_size + 255) / 256, 256, 0, stream>>>(
            (bf16*)d_out, out_size);
        return;
    }

    hipMemsetAsync(zreg, 0, zbytes, stream);
    detect_kernel<<<128, 256, 0, stream>>>(
        (const unsigned short*)feat_in, 32768, dflag);

    CvtArgs ca;
    const int cvt_n[NCVT] = {
        N_NODES * DIM, LAYERS * HEADS * DIM * DIM, LAYERS * HEADS * DIM,
        LAYERS * HEADS * DIM, LAYERS * DIM * HEADS * DIM, LAYERS * DIM,
        LAYERS * 2 * DIM * DIM, LAYERS * 2 * DIM, LAYERS * 2 * DIM };
    bf16* cvt_dst[NCVT] = { featA, cfc, cans, cand, ctw, ctb, cp1w, cp1b, cp2w };
    const int cvt_src_idx[NCVT] = { 0, 4, 5, 6, 7, 8, 9, 10, 11 };
    int total4 = 0;
    for (int s = 0; s < NCVT; ++s) {
        ca.src[s] = d_in[cvt_src_idx[s]];
        ca.dst[s] = cvt_dst[s];
        ca.n[s] = cvt_n[s];
        ca.n4[s] = (cvt_n[s] + 3) / 4;
        total4 += ca.n4[s];
    }
    cvt_all_kernel<<<(total4 + 255) / 256, 256, 0, stream>>>(ca, dflag);

    count_kernel<<<(N_EDGES + 255) / 256, 256, 0, stream>>>(dst, deg, N_EDGES);
    scan_gptr_kernel<<<1, 256, 0, stream>>>(deg, rp, gid, gptr);
    fill_kernel<<<(N_EDGES + 255) / 256, 256, 0, stream>>>(
        src, dst, rp, cursor, esrc, edst);

    const int MBLK = (N_NODES + 127) / 128;   // 157
    bf16* fin = featA;
    bf16* fout = featB;
    for (int d = 0; d < LAYERS; ++d) {
        float* gateb = gateb3 + (size_t)d * N_NODES;
        gemm_mfma<1><<<dim3(MBLK, 3), 256, 0, stream>>>(
            fin, cfc + (size_t)d * HEADS * DIM * DIM, hbuf,
            N_NODES, HEADS * DIM, DIM, nullptr, nullptr, 0,
            cans + (size_t)d * HEADS * DIM, cand + (size_t)d * HEADS * DIM,
            s_ns, s_nd, nullptr, nullptr);
        pedge_kernel<<<(N_EDGES + 255) / 256, 256, 0, stream>>>(
            esrc, edst, s_ns, s_nd, pedge);
        agg_kernel<<<(N_NODES + 3) / 4, 256, 0, stream>>>(
            (const unsigned*)hbuf, rp, esrc, pedge, aggbuf);
        gemm_mfma<0><<<dim3(MBLK, 1), 256, 0, stream>>>(
            aggbuf, ctw + (size_t)d * DIM * HEADS * DIM, fout,
            N_NODES, DIM, HEADS * DIM, ctb + (size_t)d * DIM, fin,
            (d < LAYERS - 1) ? 1 : 0, nullptr, nullptr, nullptr, nullptr,
            nullptr, nullptr);
        gemm_mfma<2><<<dim3(MBLK, 2), 256, 0, stream>>>(
            fout, cp1w + (size_t)d * 2 * DIM * DIM, nullptr,
            N_NODES, 2 * DIM, DIM, cp1b + (size_t)d * 2 * DIM, nullptr, 1,
            nullptr, nullptr, nullptr, nullptr,
            cp2w + (size_t)d * 2 * DIM, gateb);
        pool_acc<<<dim3(NGRAPH, 8), 256, 0, stream>>>(
            fout, gateb, gptr, out_acc);
        bf16* t = fin; fin = fout; fout = t;
    }
    writeout_kernel<<<(NGRAPH * DIM + 255) / 256, 256, 0, stream>>>(
        out_acc, d_out, dflag);
}

// Round 13
// 423.656 us; speedup vs baseline: 1.1489x; 1.1301x over previous
//
#include <hip/hip_runtime.h>
#include <hip/hip_bf16.h>

#define N_NODES 20000
#define N_EDGES 320000
#define DIM 128
#define HEADS 3
#define LAYERS 3
#define NGRAPH 64
#define NEG_SLOPE 0.2f

typedef const __hip_bfloat16* bfp;
typedef __hip_bfloat16 bf16;
typedef short v8s __attribute__((ext_vector_type(8)));
typedef float v4f __attribute__((ext_vector_type(4)));
typedef unsigned v3u __attribute__((ext_vector_type(3)));

#define GLD_LDS(gp, lp) \
    __builtin_amdgcn_global_load_lds( \
        (const __attribute__((address_space(1))) void*)(gp), \
        (__attribute__((address_space(3))) void*)(lp), 16, 0, 0)

__device__ __forceinline__ float b2f(unsigned short u) {
    return __uint_as_float(((unsigned)u) << 16);
}
__device__ __forceinline__ float lo2f(unsigned u) { return __uint_as_float(u << 16); }
__device__ __forceinline__ float hi2f(unsigned u) { return __uint_as_float(u & 0xffff0000u); }
__device__ __forceinline__ float leaky(float z) {
    return z >= 0.f ? z : NEG_SLOPE * z;
}
__device__ __forceinline__ unsigned packbf(float a, float b) {
    bf16 x = __float2bfloat16(a), y = __float2bfloat16(b);
    return (unsigned)*(unsigned short*)&x | ((unsigned)*(unsigned short*)&y << 16);
}
__device__ __forceinline__ unsigned short f2bfbits(float v) {
    bf16 x = __float2bfloat16(v);
    return *(unsigned short*)&x;
}

// XOR-swizzled tile staging: tile = rows x 32 bf16, granule (16B) at tile
// position row*4 + (kch ^ ((row>>1)&3)). Staging keeps 4 consecutive lanes
// inside one 64B line (coalesced, same as row-major); ds_read_b128 fragment
// reads hit all 8 dword-quad bank groups 2x over 16 lanes (2-way = free).
__device__ __forceinline__ void stage_swz(const short* base, int t0, int K,
                                          int k0, short* lds, int gidx) {
    int row = gidx >> 2, pos = gidx & 3;
    int kch = pos ^ ((row >> 1) & 3);
    GLD_LDS(base + (size_t)(t0 + row) * K + k0 + kch * 8, lds + gidx * 8);
}
__device__ __forceinline__ v8s fragx(const short* lds, int R, int q) {
    int g = R * 4 + (q ^ ((R >> 1) & 3));
    return *(const v8s*)(lds + g * 8);
}

// ---------------- dtype detection (fp32 vs bf16 storage) ----------------
__global__ void detect_kernel(const unsigned short* __restrict__ probe,
                              int nshorts, int* __restrict__ cnt) {
    int i = blockIdx.x * 256 + threadIdx.x;
    if (i < nshorts) {
        int e = (probe[i] >> 7) & 0xFF;
        if (e >= 140) atomicAdd(cnt, 1);
    }
}

// fused conversion of all float inputs into bf16 ws copies (4 elems/thread)
#define NCVT 9
struct CvtArgs {
    const void* src[NCVT];
    bf16* dst[NCVT];
    int n4[NCVT];
    int n[NCVT];
};
__global__ void cvt_all_kernel(CvtArgs args, const int* __restrict__ flag) {
    int i = blockIdx.x * 256 + threadIdx.x;
    int f = (*flag) > 8;
#pragma unroll
    for (int s = 0; s < NCVT; ++s) {
        int ns4 = args.n4[s];
        if (i < ns4) {
            int ns = args.n[s];
            int base = i * 4;
            bf16* dst = args.dst[s];
            if (f) {
                const float* sp = (const float*)args.src[s];
                if (base + 3 < ns) {
                    float4 v = *(const float4*)(sp + base);
                    ushort4 pk = { f2bfbits(v.x), f2bfbits(v.y),
                                   f2bfbits(v.z), f2bfbits(v.w) };
                    *(ushort4*)(dst + base) = pk;
                } else {
                    for (int j = 0; j < 4 && base + j < ns; ++j)
                        dst[base + j] = __float2bfloat16(sp[base + j]);
                }
            } else {
                const bf16* sp = (const bf16*)args.src[s];
                if (base + 3 < ns) {
                    *(ushort4*)(dst + base) = *(const ushort4*)(sp + base);
                } else {
                    for (int j = 0; j < 4 && base + j < ns; ++j)
                        dst[base + j] = sp[base + j];
                }
            }
            return;
        }
        i -= ns4;
    }
}

// ---------------- setup kernels ----------------

__global__ void count_kernel(const int* __restrict__ idx, int* __restrict__ cnt, int n) {
    int i = blockIdx.x * 256 + threadIdx.x;
    if (i < n) atomicAdd(&cnt[idx[i]], 1);
}

// fused: exclusive scan of deg (shfl block-scan) + gptr binary search
__global__ void scan_gptr_kernel(const int* __restrict__ cnt, int* __restrict__ ptr,
                                 const int* __restrict__ gid, int* __restrict__ gptr) {
    int tid = threadIdx.x;
    if (tid <= NGRAPH) {
        int lo = 0, hi = N_NODES;
        while (lo < hi) {
            int mid = (lo + hi) >> 1;
            if (gid[mid] < tid) lo = mid + 1; else hi = mid;
        }
        gptr[tid] = lo;
    }
    const int chunk = (N_NODES + 255) / 256;
    int b = tid * chunk, e = min(b + chunk, N_NODES);
    int loc = 0;
    for (int i = b; i < e; ++i) loc += cnt[i];
    int lane = tid & 63, wv = tid >> 6;
    int v = loc;
#pragma unroll
    for (int o = 1; o < 64; o <<= 1) {
        int t = __shfl_up(v, o);
        if (lane >= o) v += t;
    }
    __shared__ int wsum[4];
    if (lane == 63) wsum[wv] = v;
    __syncthreads();
    int wo = 0;
    for (int j = 0; j < wv; ++j) wo += wsum[j];
    int run = wo + v - loc;
    if (tid == 255) ptr[N_NODES] = wsum[0] + wsum[1] + wsum[2] + wsum[3];
    for (int i = b; i < e; ++i) { ptr[i] = run; run += cnt[i]; }
}

__global__ void fill_kernel(const int* __restrict__ src, const int* __restrict__ dst,
                            const int* __restrict__ rp, int* __restrict__ cursor,
                            int* __restrict__ esrc, int* __restrict__ edst) {
    int e = blockIdx.x * 256 + threadIdx.x;
    if (e < N_EDGES) {
        int d = dst[e];
        int pos = rp[d] + atomicAdd(&cursor[d], 1);
        esrc[pos] = src[e];
        edst[pos] = d;
    }
}

__global__ void sentinel_kernel(bf16* out, int n) {
    int i = blockIdx.x * 256 + threadIdx.x;
    if (i < n) out[i] = __float2bfloat16(2.0f);
}

// ---------------- MFMA GEMM, LDS-staged, swizzled, BM=64 --------------------
// C[M,N] = A[M,K] * B[N,K]^T, bf16 in, fp32 acc. Block tile 64x128, 4 waves,
// each wave 16 rows x 128 cols (acc = 8 x v4f = 32 VGPRs).
// MODE 0: plain C (+bias/relu/resid)
// MODE 1: head-interleaved C + fused scores (N=384, blockIdx.y == head)
// MODE 2: no C; fused gate layer-2: relu(acc+bias).p2w -> atomicAdd gateb
template <int MODE>
__global__ __launch_bounds__(256) void gemm_mfma(
    const bf16* __restrict__ A, const bf16* __restrict__ B,
    bf16* __restrict__ C, int M, int N, int K,
    const bf16* __restrict__ bias, const bf16* __restrict__ resid,
    int do_relu,
    const bf16* __restrict__ ans, const bf16* __restrict__ and_,
    float* __restrict__ s_ns, float* __restrict__ s_nd,
    const bf16* __restrict__ p2w, float* __restrict__ gateb)
{
    __shared__ short lsA[2048];    // 64 x 32
    __shared__ short lsB[4096];    // 128 x 32
    const int tid  = threadIdx.x;
    const int wave = tid >> 6;
    const int lane = tid & 63;
    const int quad = lane >> 4;
    const int r16  = lane & 15;
    const int m0 = blockIdx.x * 64;
    const int n0 = blockIdx.y * 128;
    const short* As = (const short*)A;
    const short* Bs = (const short*)B;

    v4f acc[8];
#pragma unroll
    for (int t = 0; t < 8; ++t) acc[t] = (v4f){0.f, 0.f, 0.f, 0.f};

    for (int k0 = 0; k0 < K; k0 += 32) {
        stage_swz(As, m0, K, k0, lsA, tid);            // 256 granules = A tile
        stage_swz(Bs, n0, K, k0, lsB, tid);            // B granules 0..255
        stage_swz(Bs, n0, K, k0, lsB, 256 + tid);      // B granules 256..511
        __syncthreads();
        v8s a = fragx(lsA, wave * 16 + r16, quad);
#pragma unroll
        for (int t = 0; t < 8; ++t) {
            v8s b = fragx(lsB, t * 16 + r16, quad);
            acc[t] = __builtin_amdgcn_mfma_f32_16x16x32_bf16(a, b, acc[t], 0, 0, 0);
        }
        __syncthreads();
    }

    const int mb = m0 + wave * 16;

    if (MODE == 2) {
        float pwv[8], bbv[8];
#pragma unroll
        for (int t = 0; t < 8; ++t) {
            int n = n0 + t * 16 + r16;
            pwv[t] = __bfloat162float(p2w[n]);
            bbv[t] = __bfloat162float(bias[n]);
        }
#pragma unroll
        for (int reg = 0; reg < 4; ++reg) {
            float g = 0.f;
#pragma unroll
            for (int t = 0; t < 8; ++t)
                g += fmaxf(acc[t][reg] + bbv[t], 0.f) * pwv[t];
#pragma unroll
            for (int o = 1; o < 16; o <<= 1) g += __shfl_xor(g, o);
            int m = mb + quad * 4 + reg;
            if (r16 == 0 && m < M) atomicAdd(&gateb[m], g);
        }
        return;
    }

#pragma unroll
    for (int t = 0; t < 8; ++t) {
        const int n = n0 + t * 16 + r16;
        float bb = bias ? __bfloat162float(bias[n]) : 0.f;
#pragma unroll
        for (int reg = 0; reg < 4; ++reg) {
            const int m = mb + quad * 4 + reg;
            if (m >= M) continue;
            float v = acc[t][reg];
            if (bias) {
                v += bb;
                if (do_relu) v = fmaxf(v, 0.f);
            }
            if (resid) v += __bfloat162float(resid[(size_t)m * N + n]);
            size_t idx;
            if (MODE == 1) {
                int d = n & 127, head = n >> 7;
                idx = (size_t)m * N + (size_t)((d >> 1) * 6 + head * 2 + (d & 1));
            } else {
                idx = (size_t)m * N + n;
            }
            C[idx] = __float2bfloat16(v);
        }
    }

    if (MODE == 1) {
        const int head = blockIdx.y;
        float ansv[8], andv[8];
#pragma unroll
        for (int t = 0; t < 8; ++t) {
            int dcol = t * 16 + r16;
            ansv[t] = __bfloat162float(ans[head * 128 + dcol]);
            andv[t] = __bfloat162float(and_[head * 128 + dcol]);
        }
#pragma unroll
        for (int reg = 0; reg < 4; ++reg) {
            float pns = 0.f, pnd = 0.f;
#pragma unroll
            for (int t = 0; t < 8; ++t) {
                pns += acc[t][reg] * ansv[t];
                pnd += acc[t][reg] * andv[t];
            }
#pragma unroll
            for (int o = 1; o < 16; o <<= 1) {
                pns += __shfl_xor(pns, o);
                pnd += __shfl_xor(pnd, o);
            }
            int m = mb + quad * 4 + reg;
            if (r16 == 0 && m < M) {
                s_ns[m * 3 + head] = pns;
                s_nd[m * 3 + head] = pnd;
            }
        }
    }
}

// ---------------- per-edge softmax numerators (maxless, CSR order) ----------
__global__ void pedge_kernel(const int* __restrict__ esrc,
                             const int* __restrict__ edst,
                             const float* __restrict__ s_ns,
                             const float* __restrict__ s_nd,
                             float* __restrict__ pedge) {
    int i = blockIdx.x * 256 + threadIdx.x;
    if (i >= N_EDGES) return;
    int s = esrc[i], d = edst[i];
    pedge[i * 3 + 0] = __expf(leaky(s_ns[s * 3 + 0] + s_nd[d * 3 + 0]));
    pedge[i * 3 + 1] = __expf(leaky(s_ns[s * 3 + 1] + s_nd[d * 3 + 1]));
    pedge[i * 3 + 2] = __expf(leaky(s_ns[s * 3 + 2] + s_nd[d * 3 + 2]));
}

// ---------------- aggregate: one WAVE per dst node, pure gather loop --------
__global__ __launch_bounds__(256) void agg_kernel(
    const unsigned* __restrict__ h2, const int* __restrict__ rp,
    const int* __restrict__ esrc, const float* __restrict__ pedge,
    bf16* __restrict__ agg)
{
    const int node = blockIdx.x * 4 + (threadIdx.x >> 6);
    if (node >= N_NODES) return;
    const int lane = threadIdx.x & 63;
    const int beg = rp[node], end = rp[node + 1];
    const int cnt = end - beg;
    unsigned* outp = (unsigned*)(agg + (size_t)node * (HEADS * DIM));
    if (cnt <= 0) {
        outp[lane] = 0u; outp[64 + lane] = 0u; outp[128 + lane] = 0u;
        return;
    }
    float ss0 = 0.f, ss1 = 0.f, ss2 = 0.f;
    float a0 = 0.f, a1 = 0.f, a2 = 0.f, a3 = 0.f, a4 = 0.f, a5 = 0.f;
    const float* pp = pedge + (size_t)beg * 3;
    const int* ep = esrc + beg;
#pragma unroll 4
    for (int j = 0; j < cnt; ++j) {
        int s = ep[j];
        float p0 = pp[j * 3 + 0];
        float p1 = pp[j * 3 + 1];
        float p2 = pp[j * 3 + 2];
        ss0 += p0; ss1 += p1; ss2 += p2;
        v3u w = *(const v3u*)(h2 + (size_t)s * 192 + lane * 3);
        a0 += p0 * lo2f(w.x); a1 += p0 * hi2f(w.x);
        a2 += p1 * lo2f(w.y); a3 += p1 * hi2f(w.y);
        a4 += p2 * lo2f(w.z); a5 += p2 * hi2f(w.z);
    }
    float i0 = 1.f / ss0, i1 = 1.f / ss1, i2 = 1.f / ss2;
    outp[lane]       = packbf(a0 * i0, a1 * i0);
    outp[64 + lane]  = packbf(a2 * i1, a3 * i1);
    outp[128 + lane] = packbf(a4 * i2, a5 * i2);
}

// ---------------- pooled accumulation w/ inline stats: 8 blocks/graph -------
__global__ __launch_bounds__(256) void pool_acc(
    const bf16* __restrict__ feat, const float* __restrict__ gate,
    const int* __restrict__ gptr, float* __restrict__ out_acc)
{
    const int g = blockIdx.x;
    const int chunk = blockIdx.y;
    const int tid = threadIdx.x;
    const int beg = gptr[g], end = gptr[g + 1];
    if (beg >= end) return;
    __shared__ float red[4];
    float m = -1e30f;
    for (int i = beg + tid; i < end; i += 256) m = fmaxf(m, gate[i]);
#pragma unroll
    for (int o = 32; o > 0; o >>= 1) m = fmaxf(m, __shfl_xor(m, o));
    if ((tid & 63) == 0) red[tid >> 6] = m;
    __syncthreads();
    m = fmaxf(fmaxf(red[0], red[1]), fmaxf(red[2], red[3]));
    __syncthreads();
    float s = 0.f;
    for (int i = beg + tid; i < end; i += 256) s += __expf(gate[i] - m);
#pragma unroll
    for (int o = 32; o > 0; o >>= 1) s += __shfl_xor(s, o);
    if ((tid & 63) == 0) red[tid >> 6] = s;
    __syncthreads();
    float inv = 1.f / (red[0] + red[1] + red[2] + red[3]);
    const int p = tid >> 7;
    const int c = tid & 127;
    float acc = 0.f;
    for (int i = beg + chunk * 2 + p; i < end; i += 16) {
        float w = __expf(gate[i] - m);
        acc += w * __bfloat162float(feat[(size_t)i * DIM + c]);
    }
    acc *= inv;
    atomicAdd(&out_acc[g * DIM + c], acc);
}

__global__ void writeout_kernel(const float* __restrict__ out_acc,
                                void* __restrict__ out, const int* __restrict__ flag) {
    int i = blockIdx.x * 256 + threadIdx.x;
    if (i < NGRAPH * DIM) {
        float v = out_acc[i] * (1.f / 3.f);
        if ((*flag) > 8) ((float*)out)[i] = v;
        else ((bf16*)out)[i] = __float2bfloat16(v);
    }
}

// ---------------- host launcher ----------------
extern "C" void kernel_launch(void* const* d_in, const int* in_sizes, int n_in,
                              void* d_out, int out_size, void* d_ws, size_t ws_size,
                              hipStream_t stream)
{
    const void* feat_in = d_in[0];
    const int* src = (const int*)d_in[1];
    const int* dst = (const int*)d_in[2];
    const int* gid = (const int*)d_in[3];

    char* base = (char*)d_ws;
    size_t off = 0;
    auto carve = [&](size_t bytes) -> void* {
        void* p = base + off;
        off = (off + bytes + 255) & ~(size_t)255;
        return p;
    };
    // zeroed region: dflag | deg | cursor | out_acc | gateb[3] -> ONE memset
    size_t zbytes = 256 + sizeof(int) * 2 * N_NODES + sizeof(float) * NGRAPH * DIM
                  + sizeof(float) * LAYERS * N_NODES;
    char* zreg  = (char*)carve(zbytes);
    int* dflag  = (int*)zreg;
    int* deg    = (int*)(zreg + 256);
    int* cursor = deg + N_NODES;
    float* out_acc = (float*)(cursor + N_NODES);
    float* gateb3  = out_acc + NGRAPH * DIM;
    int* rp     = (int*)carve(sizeof(int) * (N_NODES + 1));
    int* gptr   = (int*)carve(sizeof(int) * (NGRAPH + 1));
    int* esrc   = (int*)carve(sizeof(int) * N_EDGES);
    int* edst   = (int*)carve(sizeof(int) * N_EDGES);
    float* pedge = (float*)carve(sizeof(float) * N_EDGES * 3);
    float* s_ns = (float*)carve(sizeof(float) * N_NODES * HEADS);
    float* s_nd = (float*)carve(sizeof(float) * N_NODES * HEADS);
    bf16* featA = (bf16*)carve(sizeof(bf16) * N_NODES * DIM);
    bf16* featB = (bf16*)carve(sizeof(bf16) * N_NODES * DIM);
    bf16* cfc   = (bf16*)carve(sizeof(bf16) * LAYERS * HEADS * DIM * DIM);
    bf16* cans  = (bf16*)carve(sizeof(bf16) * LAYERS * HEADS * DIM);
    bf16* cand  = (bf16*)carve(sizeof(bf16) * LAYERS * HEADS * DIM);
    bf16* ctw   = (bf16*)carve(sizeof(bf16) * LAYERS * DIM * HEADS * DIM);
    bf16* ctb   = (bf16*)carve(sizeof(bf16) * LAYERS * DIM);
    bf16* cp1w  = (bf16*)carve(sizeof(bf16) * LAYERS * 2 * DIM * DIM);
    bf16* cp1b  = (bf16*)carve(sizeof(bf16) * LAYERS * 2 * DIM);
    bf16* cp2w  = (bf16*)carve(sizeof(bf16) * LAYERS * 2 * DIM);
    bf16* hbuf   = (bf16*)carve(sizeof(bf16) * N_NODES * HEADS * DIM);
    bf16* aggbuf = (bf16*)carve(sizeof(bf16) * N_NODES * HEADS * DIM);
    carve(131072);   // pad: GEMM A-tile tail overreads

    if (off > ws_size) {
        sentinel_kernel<<<(out_size + 255) / 256, 256, 0, stream>>>(
            (bf16*)d_out, out_size);
        return;
    }

    hipMemsetAsync(zreg, 0, zbytes, stream);
    detect_kernel<<<128, 256, 0, stream>>>(
        (const unsigned short*)feat_in, 32768, dflag);

    CvtArgs ca;
    const int cvt_n[NCVT] = {
        N_NODES * DIM, LAYERS * HEADS * DIM * DIM, LAYERS * HEADS * DIM,
        LAYERS * HEADS * DIM, LAYERS * DIM * HEADS * DIM, LAYERS * DIM,
        LAYERS * 2 * DIM * DIM, LAYERS * 2 * DIM, LAYERS * 2 * DIM };
    bf16* cvt_dst[NCVT] = { featA, cfc, cans, cand, ctw, ctb, cp1w, cp1b, cp2w };
    const int cvt_src_idx[NCVT] = { 0, 4, 5, 6, 7, 8, 9, 10, 11 };
    int total4 = 0;
    for (int s = 0; s < NCVT; ++s) {
        ca.src[s] = d_in[cvt_src_idx[s]];
        ca.dst[s] = cvt_dst[s];
        ca.n[s] = cvt_n[s];
        ca.n4[s] = (cvt_n[s] + 3) / 4;
        total4 += ca.n4[s];
    }
    cvt_all_kernel<<<(total4 + 255) / 256, 256, 0, stream>>>(ca, dflag);

    count_kernel<<<(N_EDGES + 255) / 256, 256, 0, stream>>>(dst, deg, N_EDGES);
    scan_gptr_kernel<<<1, 256, 0, stream>>>(deg, rp, gid, gptr);
    fill_kernel<<<(N_EDGES + 255) / 256, 256, 0, stream>>>(
        src, dst, rp, cursor, esrc, edst);

    const int MBLK = (N_NODES + 63) / 64;   // 313
    bf16* fin = featA;
    bf16* fout = featB;
    for (int d = 0; d < LAYERS; ++d) {
        float* gateb = gateb3 + (size_t)d * N_NODES;
        gemm_mfma<1><<<dim3(MBLK, 3), 256, 0, stream>>>(
            fin, cfc + (size_t)d * HEADS * DIM * DIM, hbuf,
            N_NODES, HEADS * DIM, DIM, nullptr, nullptr, 0,
            cans + (size_t)d * HEADS * DIM, cand + (size_t)d * HEADS * DIM,
            s_ns, s_nd, nullptr, nullptr);
        pedge_kernel<<<(N_EDGES + 255) / 256, 256, 0, stream>>>(
            esrc, edst, s_ns, s_nd, pedge);
        agg_kernel<<<(N_NODES + 3) / 4, 256, 0, stream>>>(
            (const unsigned*)hbuf, rp, esrc, pedge, aggbuf);
        gemm_mfma<0><<<dim3(MBLK, 1), 256, 0, stream>>>(
            aggbuf, ctw + (size_t)d * DIM * HEADS * DIM, fout,
            N_NODES, DIM, HEADS * DIM, ctb + (size_t)d * DIM, fin,
            (d < LAYERS - 1) ? 1 : 0, nullptr, nullptr, nullptr, nullptr,
            nullptr, nullptr);
        gemm_mfma<2><<<dim3(MBLK, 2), 256, 0, stream>>>(
            fout, cp1w + (size_t)d * 2 * DIM * DIM, nullptr,
            N_NODES, 2 * DIM, DIM, cp1b + (size_t)d * 2 * DIM, nullptr, 1,
            nullptr, nullptr, nullptr, nullptr,
            cp2w + (size_t)d * 2 * DIM, gateb);
        pool_acc<<<dim3(NGRAPH, 8), 256, 0, stream>>>(
            fout, gateb, gptr, out_acc);
        bf16* t = fin; fin = fout; fout = t;
    }
    writeout_kernel<<<(NGRAPH * DIM + 255) / 256, 256, 0, stream>>>(
        out_acc, d_out, dflag);
}

// Round 14
// 401.380 us; speedup vs baseline: 1.2126x; 1.0555x over previous
//
#include <hip/hip_runtime.h>
#include <hip/hip_bf16.h>

#define N_NODES 20000
#define N_EDGES 320000
#define DIM 128
#define HEADS 3
#define LAYERS 3
#define NGRAPH 64
#define NEG_SLOPE 0.2f
#define NODE_BLOCKS ((N_NODES + 63) / 64)   // 313

typedef const __hip_bfloat16* bfp;
typedef __hip_bfloat16 bf16;
typedef short v8s __attribute__((ext_vector_type(8)));
typedef float v4f __attribute__((ext_vector_type(4)));
typedef unsigned v3u __attribute__((ext_vector_type(3)));

#define GLD_LDS(gp, lp) \
    __builtin_amdgcn_global_load_lds( \
        (const __attribute__((address_space(1))) void*)(gp), \
        (__attribute__((address_space(3))) void*)(lp), 16, 0, 0)

__device__ __forceinline__ float b2f(unsigned short u) {
    return __uint_as_float(((unsigned)u) << 16);
}
__device__ __forceinline__ float lo2f(unsigned u) { return __uint_as_float(u << 16); }
__device__ __forceinline__ float hi2f(unsigned u) { return __uint_as_float(u & 0xffff0000u); }
__device__ __forceinline__ float leaky(float z) {
    return z >= 0.f ? z : NEG_SLOPE * z;
}
__device__ __forceinline__ unsigned packbf(float a, float b) {
    bf16 x = __float2bfloat16(a), y = __float2bfloat16(b);
    return (unsigned)*(unsigned short*)&x | ((unsigned)*(unsigned short*)&y << 16);
}
__device__ __forceinline__ unsigned short f2bfbits(float v) {
    bf16 x = __float2bfloat16(v);
    return *(unsigned short*)&x;
}

// XOR-swizzled tile staging (validated R13): granule (16B) of row r, kchunk c
// stored at tile pos r*4 + (c ^ ((r>>1)&3)). Coalesced staging (4 lanes in one
// 64B line) AND 2-way-only LDS bank aliasing on ds_read_b128 fragments.
__device__ __forceinline__ void stage_swz(const short* base, int t0, int K,
                                          int k0, short* lds, int gidx) {
    int row = gidx >> 2, pos = gidx & 3;
    int kch = pos ^ ((row >> 1) & 3);
    GLD_LDS(base + (size_t)(t0 + row) * K + k0 + kch * 8, lds + gidx * 8);
}
__device__ __forceinline__ v8s fragx(const short* lds, int R, int q) {
    int g = R * 4 + (q ^ ((R >> 1) & 3));
    return *(const v8s*)(lds + g * 8);
}

// ---------------- init: zero workspace region + dtype detect ----------------
__global__ void init_kernel(unsigned* __restrict__ z, int nzd,
                            const unsigned short* __restrict__ probe,
                            int* __restrict__ dflag) {
    int gid = blockIdx.x * 256 + threadIdx.x;
    for (int i = gid; i < nzd; i += gridDim.x * 256) z[i] = 0u;
    if (blockIdx.x == 0) {
        int c = 0;
#pragma unroll
        for (int j = 0; j < 64; ++j) {
            unsigned short u = probe[threadIdx.x * 64 + j];
            c += (((u >> 7) & 0xFF) >= 140) ? 1 : 0;
        }
        for (int o = 32; o > 0; o >>= 1) c += __shfl_down(c, o);
        __shared__ int r[4];
        if ((threadIdx.x & 63) == 0) r[threadIdx.x >> 6] = c;
        __syncthreads();
        if (threadIdx.x == 0) *dflag = r[0] + r[1] + r[2] + r[3];
    }
}

// ---------------- fused cvt (all float inputs -> bf16) + edge histogram -----
#define NCVT 9
struct CvtArgs {
    const void* src[NCVT];
    bf16* dst[NCVT];
    int n4[NCVT];
    int n[NCVT];
};
__global__ void cvtcount_kernel(CvtArgs args, const int* __restrict__ flag,
                                const int* __restrict__ dst, int* __restrict__ deg,
                                int cvtBlocks) {
    if ((int)blockIdx.x >= cvtBlocks) {
        int e = (blockIdx.x - cvtBlocks) * 256 + threadIdx.x;
        if (e < N_EDGES) atomicAdd(&deg[dst[e]], 1);
        return;
    }
    int i = blockIdx.x * 256 + threadIdx.x;
    int f = (*flag) > 8;
#pragma unroll
    for (int s = 0; s < NCVT; ++s) {
        int ns4 = args.n4[s];
        if (i < ns4) {
            int ns = args.n[s];
            int base = i * 4;
            bf16* dstp = args.dst[s];
            if (f) {
                const float* sp = (const float*)args.src[s];
                if (base + 3 < ns) {
                    float4 v = *(const float4*)(sp + base);
                    ushort4 pk = { f2bfbits(v.x), f2bfbits(v.y),
                                   f2bfbits(v.z), f2bfbits(v.w) };
                    *(ushort4*)(dstp + base) = pk;
                } else {
                    for (int j = 0; j < 4 && base + j < ns; ++j)
                        dstp[base + j] = __float2bfloat16(sp[base + j]);
                }
            } else {
                const bf16* sp = (const bf16*)args.src[s];
                if (base + 3 < ns) {
                    *(ushort4*)(dstp + base) = *(const ushort4*)(sp + base);
                } else {
                    for (int j = 0; j < 4 && base + j < ns; ++j)
                        dstp[base + j] = sp[base + j];
                }
            }
            return;
        }
        i -= ns4;
    }
}

// ---------------- fused: deg scan (shfl block-scan) + gptr binary search ----
__global__ void scan_gptr_kernel(const int* __restrict__ cnt, int* __restrict__ ptr,
                                 const int* __restrict__ gid, int* __restrict__ gptr) {
    int tid = threadIdx.x;
    if (tid <= NGRAPH) {
        int lo = 0, hi = N_NODES;
        while (lo < hi) {
            int mid = (lo + hi) >> 1;
            if (gid[mid] < tid) lo = mid + 1; else hi = mid;
        }
        gptr[tid] = lo;
    }
    const int chunk = (N_NODES + 255) / 256;
    int b = tid * chunk, e = min(b + chunk, N_NODES);
    int loc = 0;
    for (int i = b; i < e; ++i) loc += cnt[i];
    int lane = tid & 63, wv = tid >> 6;
    int v = loc;
#pragma unroll
    for (int o = 1; o < 64; o <<= 1) {
        int t = __shfl_up(v, o);
        if (lane >= o) v += t;
    }
    __shared__ int wsum[4];
    if (lane == 63) wsum[wv] = v;
    __syncthreads();
    int wo = 0;
    for (int j = 0; j < wv; ++j) wo += wsum[j];
    int run = wo + v - loc;
    if (tid == 255) ptr[N_NODES] = wsum[0] + wsum[1] + wsum[2] + wsum[3];
    for (int i = b; i < e; ++i) { ptr[i] = run; run += cnt[i]; }
}

__global__ void fill_kernel(const int* __restrict__ src, const int* __restrict__ dst,
                            const int* __restrict__ rp, int* __restrict__ cursor,
                            int* __restrict__ esrc, int* __restrict__ edst) {
    int e = blockIdx.x * 256 + threadIdx.x;
    if (e < N_EDGES) {
        int d = dst[e];
        int pos = rp[d] + atomicAdd(&cursor[d], 1);
        esrc[pos] = src[e];
        edst[pos] = d;
    }
}

__global__ void sentinel_kernel(bf16* out, int n) {
    int i = blockIdx.x * 256 + threadIdx.x;
    if (i < n) out[i] = __float2bfloat16(2.0f);
}

// ---------------- MFMA GEMM, LDS-staged, swizzled, BM=64 --------------------
// MODE 0: plain C (+bias/relu/resid).  MODE 2: fused gate layer-2.
template <int MODE>
__global__ __launch_bounds__(256) void gemm_mfma(
    const bf16* __restrict__ A, const bf16* __restrict__ B,
    bf16* __restrict__ C, int M, int N, int K,
    const bf16* __restrict__ bias, const bf16* __restrict__ resid,
    int do_relu, const bf16* __restrict__ p2w, float* __restrict__ gateb)
{
    __shared__ short lsA[2048];
    __shared__ short lsB[4096];
    const int tid  = threadIdx.x;
    const int wave = tid >> 6;
    const int lane = tid & 63;
    const int quad = lane >> 4;
    const int r16  = lane & 15;
    const int m0 = blockIdx.x * 64;
    const int n0 = blockIdx.y * 128;
    const short* As = (const short*)A;
    const short* Bs = (const short*)B;

    v4f acc[8];
#pragma unroll
    for (int t = 0; t < 8; ++t) acc[t] = (v4f){0.f, 0.f, 0.f, 0.f};

    for (int k0 = 0; k0 < K; k0 += 32) {
        stage_swz(As, m0, K, k0, lsA, tid);
        stage_swz(Bs, n0, K, k0, lsB, tid);
        stage_swz(Bs, n0, K, k0, lsB, 256 + tid);
        __syncthreads();
        v8s a = fragx(lsA, wave * 16 + r16, quad);
#pragma unroll
        for (int t = 0; t < 8; ++t) {
            v8s b = fragx(lsB, t * 16 + r16, quad);
            acc[t] = __builtin_amdgcn_mfma_f32_16x16x32_bf16(a, b, acc[t], 0, 0, 0);
        }
        __syncthreads();
    }

    const int mb = m0 + wave * 16;

    if (MODE == 2) {
        float pwv[8], bbv[8];
#pragma unroll
        for (int t = 0; t < 8; ++t) {
            int n = n0 + t * 16 + r16;
            pwv[t] = __bfloat162float(p2w[n]);
            bbv[t] = __bfloat162float(bias[n]);
        }
#pragma unroll
        for (int reg = 0; reg < 4; ++reg) {
            float g = 0.f;
#pragma unroll
            for (int t = 0; t < 8; ++t)
                g += fmaxf(acc[t][reg] + bbv[t], 0.f) * pwv[t];
#pragma unroll
            for (int o = 1; o < 16; o <<= 1) g += __shfl_xor(g, o);
            int m = mb + quad * 4 + reg;
            if (r16 == 0 && m < M) atomicAdd(&gateb[m], g);
        }
        return;
    }

#pragma unroll
    for (int t = 0; t < 8; ++t) {
        const int n = n0 + t * 16 + r16;
        float bb = bias ? __bfloat162float(bias[n]) : 0.f;
#pragma unroll
        for (int reg = 0; reg < 4; ++reg) {
            const int m = mb + quad * 4 + reg;
            if (m >= M) continue;
            float v = acc[t][reg];
            if (bias) {
                v += bb;
                if (do_relu) v = fmaxf(v, 0.f);
            }
            if (resid) v += __bfloat162float(resid[(size_t)m * N + n]);
            C[(size_t)m * N + n] = __float2bfloat16(v);
        }
    }
}

// ---------------- fc body (head-interleaved C + fused scores) ---------------
__device__ __forceinline__ void fc_block(
    const short* As, const short* Bs, bf16* __restrict__ C, int M,
    const bf16* __restrict__ ans, const bf16* __restrict__ and_,
    float* __restrict__ s_ns, float* __restrict__ s_nd,
    short* lsA, short* lsB, int tid, int mbx, int head)
{
    const int wave = tid >> 6;
    const int lane = tid & 63;
    const int quad = lane >> 4;
    const int r16  = lane & 15;
    const int m0 = mbx * 64;
    const int n0 = head * 128;
    const int N = HEADS * DIM, K = DIM;

    v4f acc[8];
#pragma unroll
    for (int t = 0; t < 8; ++t) acc[t] = (v4f){0.f, 0.f, 0.f, 0.f};

    for (int k0 = 0; k0 < K; k0 += 32) {
        stage_swz(As, m0, K, k0, lsA, tid);
        stage_swz(Bs, n0, K, k0, lsB, tid);
        stage_swz(Bs, n0, K, k0, lsB, 256 + tid);
        __syncthreads();
        v8s a = fragx(lsA, wave * 16 + r16, quad);
#pragma unroll
        for (int t = 0; t < 8; ++t) {
            v8s b = fragx(lsB, t * 16 + r16, quad);
            acc[t] = __builtin_amdgcn_mfma_f32_16x16x32_bf16(a, b, acc[t], 0, 0, 0);
        }
        __syncthreads();
    }

    const int mb = m0 + wave * 16;
#pragma unroll
    for (int t = 0; t < 8; ++t) {
        const int dcol = t * 16 + r16;
        const size_t cix = (size_t)((dcol >> 1) * 6 + head * 2 + (dcol & 1));
#pragma unroll
        for (int reg = 0; reg < 4; ++reg) {
            const int m = mb + quad * 4 + reg;
            if (m >= M) continue;
            C[(size_t)m * N + cix] = __float2bfloat16(acc[t][reg]);
        }
    }
    float ansv[8], andv[8];
#pragma unroll
    for (int t = 0; t < 8; ++t) {
        int dcol = t * 16 + r16;
        ansv[t] = __bfloat162float(ans[head * 128 + dcol]);
        andv[t] = __bfloat162float(and_[head * 128 + dcol]);
    }
#pragma unroll
    for (int reg = 0; reg < 4; ++reg) {
        float pns = 0.f, pnd = 0.f;
#pragma unroll
        for (int t = 0; t < 8; ++t) {
            pns += acc[t][reg] * ansv[t];
            pnd += acc[t][reg] * andv[t];
        }
#pragma unroll
        for (int o = 1; o < 16; o <<= 1) {
            pns += __shfl_xor(pns, o);
            pnd += __shfl_xor(pnd, o);
        }
        int m = mb + quad * 4 + reg;
        if (r16 == 0 && m < M) {
            s_ns[m * 3 + head] = pns;
            s_nd[m * 3 + head] = pnd;
        }
    }
}

// ---------------- merged: pool_acc(layer d-1) + fc(layer d) -----------------
// Blocks [0, poolBlocks): pool (indep of fc; both read only prev fout/gateb).
// Blocks [poolBlocks, +939): fc with fused scores.
__global__ __launch_bounds__(256) void poolfc_kernel(
    const bf16* __restrict__ pfeat, const float* __restrict__ gate,
    const int* __restrict__ gptr, float* __restrict__ out_acc,
    const bf16* __restrict__ A, const bf16* __restrict__ B,
    bf16* __restrict__ C, int M,
    const bf16* __restrict__ ans, const bf16* __restrict__ and_,
    float* __restrict__ s_ns, float* __restrict__ s_nd,
    int poolBlocks)
{
    __shared__ short lsA[2048];
    __shared__ short lsB[4096];
    __shared__ float red[4];
    const int tid = threadIdx.x;
    if ((int)blockIdx.x < poolBlocks) {
        const int g = blockIdx.x >> 3;
        const int chunk = blockIdx.x & 7;
        const int beg = gptr[g], end = gptr[g + 1];
        if (beg >= end) return;
        float m = -1e30f;
        for (int i = beg + tid; i < end; i += 256) m = fmaxf(m, gate[i]);
#pragma unroll
        for (int o = 32; o > 0; o >>= 1) m = fmaxf(m, __shfl_xor(m, o));
        if ((tid & 63) == 0) red[tid >> 6] = m;
        __syncthreads();
        m = fmaxf(fmaxf(red[0], red[1]), fmaxf(red[2], red[3]));
        __syncthreads();
        float s = 0.f;
        for (int i = beg + tid; i < end; i += 256) s += __expf(gate[i] - m);
#pragma unroll
        for (int o = 32; o > 0; o >>= 1) s += __shfl_xor(s, o);
        if ((tid & 63) == 0) red[tid >> 6] = s;
        __syncthreads();
        float inv = 1.f / (red[0] + red[1] + red[2] + red[3]);
        const int p = tid >> 7;
        const int c = tid & 127;
        float acc = 0.f;
        for (int i = beg + chunk * 2 + p; i < end; i += 16) {
            float w = __expf(gate[i] - m);
            acc += w * __bfloat162float(pfeat[(size_t)i * DIM + c]);
        }
        acc *= inv;
        atomicAdd(&out_acc[g * DIM + c], acc);
        return;
    }
    const int t = blockIdx.x - poolBlocks;
    const int mbx = t % NODE_BLOCKS;
    const int head = t / NODE_BLOCKS;
    fc_block((const short*)A, (const short*)B, C, M, ans, and_, s_ns, s_nd,
             lsA, lsB, tid, mbx, head);
}

// ---------------- per-edge softmax numerators (maxless, CSR order) ----------
__global__ void pedge_kernel(const int* __restrict__ esrc,
                             const int* __restrict__ edst,
                             const float* __restrict__ s_ns,
                             const float* __restrict__ s_nd,
                             float* __restrict__ pedge) {
    int i = blockIdx.x * 256 + threadIdx.x;
    if (i >= N_EDGES) return;
    int s = esrc[i], d = edst[i];
    pedge[i * 3 + 0] = __expf(leaky(s_ns[s * 3 + 0] + s_nd[d * 3 + 0]));
    pedge[i * 3 + 1] = __expf(leaky(s_ns[s * 3 + 1] + s_nd[d * 3 + 1]));
    pedge[i * 3 + 2] = __expf(leaky(s_ns[s * 3 + 2] + s_nd[d * 3 + 2]));
}

// ---------------- aggregate: one WAVE per dst node, pure gather loop --------
__global__ __launch_bounds__(256) void agg_kernel(
    const unsigned* __restrict__ h2, const int* __restrict__ rp,
    const int* __restrict__ esrc, const float* __restrict__ pedge,
    bf16* __restrict__ agg)
{
    const int node = blockIdx.x * 4 + (threadIdx.x >> 6);
    if (node >= N_NODES) return;
    const int lane = threadIdx.x & 63;
    const int beg = rp[node], end = rp[node + 1];
    const int cnt = end - beg;
    unsigned* outp = (unsigned*)(agg + (size_t)node * (HEADS * DIM));
    if (cnt <= 0) {
        outp[lane] = 0u; outp[64 + lane] = 0u; outp[128 + lane] = 0u;
        return;
    }
    float ss0 = 0.f, ss1 = 0.f, ss2 = 0.f;
    float a0 = 0.f, a1 = 0.f, a2 = 0.f, a3 = 0.f, a4 = 0.f, a5 = 0.f;
    const float* pp = pedge + (size_t)beg * 3;
    const int* ep = esrc + beg;
#pragma unroll 4
    for (int j = 0; j < cnt; ++j) {
        int s = ep[j];
        float p0 = pp[j * 3 + 0];
        float p1 = pp[j * 3 + 1];
        float p2 = pp[j * 3 + 2];
        ss0 += p0; ss1 += p1; ss2 += p2;
        v3u w = *(const v3u*)(h2 + (size_t)s * 192 + lane * 3);
        a0 += p0 * lo2f(w.x); a1 += p0 * hi2f(w.x);
        a2 += p1 * lo2f(w.y); a3 += p1 * hi2f(w.y);
        a4 += p2 * lo2f(w.z); a5 += p2 * hi2f(w.z);
    }
    float i0 = 1.f / ss0, i1 = 1.f / ss1, i2 = 1.f / ss2;
    outp[lane]       = packbf(a0 * i0, a1 * i0);
    outp[64 + lane]  = packbf(a2 * i1, a3 * i1);
    outp[128 + lane] = packbf(a4 * i2, a5 * i2);
}

// ---------------- standalone pool (final layer) -----------------------------
__global__ __launch_bounds__(256) void pool_acc(
    const bf16* __restrict__ feat, const float* __restrict__ gate,
    const int* __restrict__ gptr, float* __restrict__ out_acc)
{
    const int g = blockIdx.x;
    const int chunk = blockIdx.y;
    const int tid = threadIdx.x;
    const int beg = gptr[g], end = gptr[g + 1];
    if (beg >= end) return;
    __shared__ float red[4];
    float m = -1e30f;
    for (int i = beg + tid; i < end; i += 256) m = fmaxf(m, gate[i]);
#pragma unroll
    for (int o = 32; o > 0; o >>= 1) m = fmaxf(m, __shfl_xor(m, o));
    if ((tid & 63) == 0) red[tid >> 6] = m;
    __syncthreads();
    m = fmaxf(fmaxf(red[0], red[1]), fmaxf(red[2], red[3]));
    __syncthreads();
    float s = 0.f;
    for (int i = beg + tid; i < end; i += 256) s += __expf(gate[i] - m);
#pragma unroll
    for (int o = 32; o > 0; o >>= 1) s += __shfl_xor(s, o);
    if ((tid & 63) == 0) red[tid >> 6] = s;
    __syncthreads();
    float inv = 1.f / (red[0] + red[1] + red[2] + red[3]);
    const int p = tid >> 7;
    const int c = tid & 127;
    float acc = 0.f;
    for (int i = beg + chunk * 2 + p; i < end; i += 16) {
        float w = __expf(gate[i] - m);
        acc += w * __bfloat162float(feat[(size_t)i * DIM + c]);
    }
    acc *= inv;
    atomicAdd(&out_acc[g * DIM + c], acc);
}

__global__ void writeout_kernel(const float* __restrict__ out_acc,
                                void* __restrict__ out, const int* __restrict__ flag) {
    int i = blockIdx.x * 256 + threadIdx.x;
    if (i < NGRAPH * DIM) {
        float v = out_acc[i] * (1.f / 3.f);
        if ((*flag) > 8) ((float*)out)[i] = v;
        else ((bf16*)out)[i] = __float2bfloat16(v);
    }
}

// ---------------- host launcher ----------------
extern "C" void kernel_launch(void* const* d_in, const int* in_sizes, int n_in,
                              void* d_out, int out_size, void* d_ws, size_t ws_size,
                              hipStream_t stream)
{
    const void* feat_in = d_in[0];
    const int* src = (const int*)d_in[1];
    const int* dst = (const int*)d_in[2];
    const int* gid = (const int*)d_in[3];

    char* base = (char*)d_ws;
    size_t off = 0;
    auto carve = [&](size_t bytes) -> void* {
        void* p = base + off;
        off = (off + bytes + 255) & ~(size_t)255;
        return p;
    };
    int* dflag = (int*)carve(256);   // NOT zeroed; init block 0 stores it
    // zeroed region: deg | cursor | out_acc | gateb[3]
    size_t zbytes = sizeof(int) * 2 * N_NODES + sizeof(float) * NGRAPH * DIM
                  + sizeof(float) * LAYERS * N_NODES;
    char* zreg  = (char*)carve(zbytes);
    int* deg    = (int*)zreg;
    int* cursor = deg + N_NODES;
    float* out_acc = (float*)(cursor + N_NODES);
    float* gateb3  = out_acc + NGRAPH * DIM;
    int* rp     = (int*)carve(sizeof(int) * (N_NODES + 1));
    int* gptr   = (int*)carve(sizeof(int) * (NGRAPH + 1));
    int* esrc   = (int*)carve(sizeof(int) * N_EDGES);
    int* edst   = (int*)carve(sizeof(int) * N_EDGES);
    float* pedge = (float*)carve(sizeof(float) * N_EDGES * 3);
    float* s_ns = (float*)carve(sizeof(float) * N_NODES * HEADS);
    float* s_nd = (float*)carve(sizeof(float) * N_NODES * HEADS);
    bf16* featA = (bf16*)carve(sizeof(bf16) * N_NODES * DIM);
    bf16* featB = (bf16*)carve(sizeof(bf16) * N_NODES * DIM);
    bf16* cfc   = (bf16*)carve(sizeof(bf16) * LAYERS * HEADS * DIM * DIM);
    bf16* cans  = (bf16*)carve(sizeof(bf16) * LAYERS * HEADS * DIM);
    bf16* cand  = (bf16*)carve(sizeof(bf16) * LAYERS * HEADS * DIM);
    bf16* ctw   = (bf16*)carve(sizeof(bf16) * LAYERS * DIM * HEADS * DIM);
    bf16* ctb   = (bf16*)carve(sizeof(bf16) * LAYERS * DIM);
    bf16* cp1w  = (bf16*)carve(sizeof(bf16) * LAYERS * 2 * DIM * DIM);
    bf16* cp1b  = (bf16*)carve(sizeof(bf16) * LAYERS * 2 * DIM);
    bf16* cp2w  = (bf16*)carve(sizeof(bf16) * LAYERS * 2 * DIM);
    bf16* hbuf   = (bf16*)carve(sizeof(bf16) * N_NODES * HEADS * DIM);
    bf16* aggbuf = (bf16*)carve(sizeof(bf16) * N_NODES * HEADS * DIM);
    carve(131072);   // pad: GEMM A-tile tail overreads

    if (off > ws_size) {
        sentinel_kernel<<<(out_size + 255) / 256, 256, 0, stream>>>(
            (bf16*)d_out, out_size);
        return;
    }

    init_kernel<<<128, 256, 0, stream>>>(
        (unsigned*)zreg, (int)(zbytes / 4), (const unsigned short*)feat_in, dflag);

    CvtArgs ca;
    const int cvt_n[NCVT] = {
        N_NODES * DIM, LAYERS * HEADS * DIM * DIM, LAYERS * HEADS * DIM,
        LAYERS * HEADS * DIM, LAYERS * DIM * HEADS * DIM, LAYERS * DIM,
        LAYERS * 2 * DIM * DIM, LAYERS * 2 * DIM, LAYERS * 2 * DIM };
    bf16* cvt_dst[NCVT] = { featA, cfc, cans, cand, ctw, ctb, cp1w, cp1b, cp2w };
    const int cvt_src_idx[NCVT] = { 0, 4, 5, 6, 7, 8, 9, 10, 11 };
    int total4 = 0;
    for (int s = 0; s < NCVT; ++s) {
        ca.src[s] = d_in[cvt_src_idx[s]];
        ca.dst[s] = cvt_dst[s];
        ca.n[s] = cvt_n[s];
        ca.n4[s] = (cvt_n[s] + 3) / 4;
        total4 += ca.n4[s];
    }
    const int cvtBlocks = (total4 + 255) / 256;
    const int cntBlocks = (N_EDGES + 255) / 256;
    cvtcount_kernel<<<cvtBlocks + cntBlocks, 256, 0, stream>>>(
        ca, dflag, dst, deg, cvtBlocks);

    scan_gptr_kernel<<<1, 256, 0, stream>>>(deg, rp, gid, gptr);
    fill_kernel<<<cntBlocks, 256, 0, stream>>>(src, dst, rp, cursor, esrc, edst);

    bf16* fin = featA;
    bf16* fout = featB;
    for (int d = 0; d < LAYERS; ++d) {
        float* gateb = gateb3 + (size_t)d * N_NODES;
        const int poolBlocks = (d == 0) ? 0 : NGRAPH * 8;
        // merged: pool(d-1) [if d>0] + fc(d) with fused scores
        poolfc_kernel<<<poolBlocks + NODE_BLOCKS * 3, 256, 0, stream>>>(
            fin, (d == 0) ? nullptr : gateb3 + (size_t)(d - 1) * N_NODES,
            gptr, out_acc,
            fin, cfc + (size_t)d * HEADS * DIM * DIM, hbuf, N_NODES,
            cans + (size_t)d * HEADS * DIM, cand + (size_t)d * HEADS * DIM,
            s_ns, s_nd, poolBlocks);
        pedge_kernel<<<(N_EDGES + 255) / 256, 256, 0, stream>>>(
            esrc, edst, s_ns, s_nd, pedge);
        agg_kernel<<<(N_NODES + 3) / 4, 256, 0, stream>>>(
            (const unsigned*)hbuf, rp, esrc, pedge, aggbuf);
        gemm_mfma<0><<<dim3(NODE_BLOCKS, 1), 256, 0, stream>>>(
            aggbuf, ctw + (size_t)d * DIM * HEADS * DIM, fout,
            N_NODES, DIM, HEADS * DIM, ctb + (size_t)d * DIM, fin,
            (d < LAYERS - 1) ? 1 : 0, nullptr, nullptr);
        gemm_mfma<2><<<dim3(NODE_BLOCKS, 2), 256, 0, stream>>>(
            fout, cp1w + (size_t)d * 2 * DIM * DIM, nullptr,
            N_NODES, 2 * DIM, DIM, cp1b + (size_t)d * 2 * DIM, nullptr, 1,
            cp2w + (size_t)d * 2 * DIM, gateb);
        bf16* t = fin; fin = fout; fout = t;
    }
    // final layer pool (fin now holds layer-2 output after swap)
    pool_acc<<<dim3(NGRAPH, 8), 256, 0, stream>>>(
        fin, gateb3 + (size_t)2 * N_NODES, gptr, out_acc);
    writeout_kernel<<<(NGRAPH * DIM + 255) / 256, 256, 0, stream>>>(
        out_acc, d_out, dflag);
}